// Round 1
// baseline (2489.461 us; speedup 1.0000x reference)
//
#include <hip/hip_runtime.h>
#include <hip/hip_bf16.h>
#include <math.h>

#define DIM 128

// ---------------- small utility kernels ----------------

__global__ __launch_bounds__(256) void k_zero(int* __restrict__ p, int n) {
    int i = blockIdx.x * 256 + threadIdx.x;
    if (i < n) p[i] = 0;
}

__global__ __launch_bounds__(256) void k_degree(const int* __restrict__ dst,
                                                int* __restrict__ cnt, int E) {
    int e = blockIdx.x * 256 + threadIdx.x;
    if (e < E) atomicAdd(&cnt[dst[e]], 1);
}

__global__ __launch_bounds__(256) void k_dinv(const int* __restrict__ cnt,
                                              float* __restrict__ dinv, int n) {
    int i = blockIdx.x * 256 + threadIdx.x;
    if (i < n) dinv[i] = rsqrtf((float)(cnt[i] + 1));  // +1 = self loop; deg>0 always
}

// single-block exclusive scan of cnt[0..n) -> row_ptr[0..n], also copy into fill[]
__global__ __launch_bounds__(1024) void k_scan(const int* __restrict__ cnt,
                                               int* __restrict__ row_ptr,
                                               int* __restrict__ fill, int n) {
    __shared__ int wsum[16];
    int t = threadIdx.x;
    int lane = t & 63, wid = t >> 6;
    int chunk = (((n + 1023) >> 10) + 3) & ~3;
    int start = t * chunk;
    int end = start + chunk; if (end > n) end = n;

    int s = 0;
    for (int i = start; i < end; ++i) s += cnt[i];

    // wave-level inclusive scan of per-thread sums
    int incl = s;
    #pragma unroll
    for (int off = 1; off < 64; off <<= 1) {
        int y = __shfl_up(incl, off, 64);
        if (lane >= off) incl += y;
    }
    if (lane == 63) wsum[wid] = incl;
    __syncthreads();
    if (t == 0) {
        int run = 0;
        #pragma unroll
        for (int w = 0; w < 16; ++w) { int v = wsum[w]; wsum[w] = run; run += v; }
    }
    __syncthreads();
    int excl = wsum[wid] + incl - s;  // exclusive prefix of this thread's chunk

    int run = excl;
    for (int i = start; i < end; ++i) {
        row_ptr[i] = run;
        fill[i]    = run;
        run += cnt[i];
    }
    if (start < n && end == n) row_ptr[n] = run;  // total == E
}

__global__ __launch_bounds__(256) void k_bucket(const int* __restrict__ src,
                                                const int* __restrict__ dst,
                                                int* __restrict__ fill,
                                                int* __restrict__ srcs, int E) {
    int e = blockIdx.x * 256 + threadIdx.x;
    if (e < E) {
        int d = dst[e];
        int pos = atomicAdd(&fill[d], 1);
        srcs[pos] = src[e];
    }
}

// ---------------- GEMM1: xw = x @ W  (W 128x128 in LDS) ----------------

#define F4(v, i) (((const float*)&(v))[i])

__global__ __launch_bounds__(256) void k_gemm1(const float* __restrict__ X,
                                               const float* __restrict__ W,
                                               float* __restrict__ XW, int n) {
    __shared__ float Wl[128 * 128];
    __shared__ float Xs[16 * 128];
    int t = threadIdx.x;
    // stage W (64KB)
    for (int i = t; i < 4096; i += 256)
        ((float4*)Wl)[i] = ((const float4*)W)[i];
    // stage 16 rows of X
    int r0 = blockIdx.x * 16;
    int rows = n - r0; if (rows > 16) rows = 16;
    int nf4 = rows * 32;
    for (int i = t; i < nf4; i += 256)
        ((float4*)Xs)[i] = ((const float4*)(X + (size_t)r0 * DIM))[i];
    __syncthreads();

    int c0 = t & 63, rg = t >> 6;           // 4 row-groups x 4 rows, cols {c0, c0+64}
    const float* xs = Xs + rg * 4 * DIM;
    float acc[4][2] = {};
    for (int k = 0; k < 128; k += 4) {
        float4 a0 = *(const float4*)(xs + 0 * DIM + k);
        float4 a1 = *(const float4*)(xs + 1 * DIM + k);
        float4 a2 = *(const float4*)(xs + 2 * DIM + k);
        float4 a3 = *(const float4*)(xs + 3 * DIM + k);
        #pragma unroll
        for (int kk = 0; kk < 4; ++kk) {
            float w0 = Wl[(k + kk) * 128 + c0];
            float w1 = Wl[(k + kk) * 128 + c0 + 64];
            acc[0][0] += F4(a0, kk) * w0;  acc[0][1] += F4(a0, kk) * w1;
            acc[1][0] += F4(a1, kk) * w0;  acc[1][1] += F4(a1, kk) * w1;
            acc[2][0] += F4(a2, kk) * w0;  acc[2][1] += F4(a2, kk) * w1;
            acc[3][0] += F4(a3, kk) * w0;  acc[3][1] += F4(a3, kk) * w1;
        }
    }
    #pragma unroll
    for (int r = 0; r < 4; ++r) {
        int row = r0 + rg * 4 + r;
        if (row < n) {
            XW[(size_t)row * DIM + c0]      = acc[r][0];
            XW[(size_t)row * DIM + c0 + 64] = acc[r][1];
        }
    }
}

// ---------------- gather: h_cur = sum_{e in CSR[d]} xw[src]*norm + self + bias ----

__global__ __launch_bounds__(256) void k_gather(const float* __restrict__ XW,
                                                const float* __restrict__ dinv,
                                                const int* __restrict__ row_ptr,
                                                const int* __restrict__ srcs,
                                                const float* __restrict__ bias,
                                                float* __restrict__ Out, int n) {
    int node = blockIdx.x * 4 + (threadIdx.x >> 6);   // one wave per node
    if (node >= n) return;
    int lane = threadIdx.x & 63;
    int c = lane * 2;

    float di = dinv[node];
    float2 xv = *(const float2*)(XW + (size_t)node * DIM + c);
    float accx = bias[c]     + xv.x * di * di;   // self loop + bias
    float accy = bias[c + 1] + xv.y * di * di;

    int e = row_ptr[node], end = row_ptr[node + 1];
    for (; e + 3 < end; e += 4) {   // 4-wide unroll for memory-level parallelism
        int s0 = srcs[e], s1 = srcs[e + 1], s2 = srcs[e + 2], s3 = srcs[e + 3];
        float n0 = dinv[s0] * di, n1 = dinv[s1] * di, n2 = dinv[s2] * di, n3 = dinv[s3] * di;
        float2 v0 = *(const float2*)(XW + (size_t)s0 * DIM + c);
        float2 v1 = *(const float2*)(XW + (size_t)s1 * DIM + c);
        float2 v2 = *(const float2*)(XW + (size_t)s2 * DIM + c);
        float2 v3 = *(const float2*)(XW + (size_t)s3 * DIM + c);
        accx += v0.x * n0 + v1.x * n1 + v2.x * n2 + v3.x * n3;
        accy += v0.y * n0 + v1.y * n1 + v2.y * n2 + v3.y * n3;
    }
    for (; e < end; ++e) {
        int s = srcs[e];
        float nrm = dinv[s] * di;
        float2 v = *(const float2*)(XW + (size_t)s * DIM + c);
        accx += v.x * nrm;  accy += v.y * nrm;
    }
    float2 o; o.x = accx; o.y = accy;
    *(float2*)(Out + (size_t)node * DIM + c) = o;
}

// ---------------- fused GRU cell ----------------
// gi = h_cur @ W_ih^T + b_ih ; gh = x_prev @ W_hh^T + b_hh
// r=sig(i_r+h_r); z=sig(i_z+h_z); n=tanh(i_n + r*h_n); out=(1-z)*n + z*x_prev
// In-place on Out (= h_cur): rows staged to LDS before overwrite.

__global__ __launch_bounds__(256) void k_gru(const float* __restrict__ Hc,
                                             const float* __restrict__ Xp,
                                             const float* __restrict__ Wih,
                                             const float* __restrict__ Whh,
                                             const float* __restrict__ bih,
                                             const float* __restrict__ bhh,
                                             float* __restrict__ Out, int n) {
    __shared__ float Ah[16 * DIM];
    __shared__ float Ax[16 * DIM];
    int t = threadIdx.x;
    int r0 = blockIdx.x * 16;
    int rows = n - r0; if (rows > 16) rows = 16;
    int nf4 = rows * 32;
    size_t base = (size_t)r0 * DIM;
    for (int i = t; i < nf4; i += 256) {
        ((float4*)Ah)[i] = ((const float4*)(Hc + base))[i];
        ((float4*)Ax)[i] = ((const float4*)(Xp + base))[i];
    }
    __syncthreads();

    int c0 = t & 63, rg = t >> 6;                 // rows rg*4..rg*4+3, cols {c0,c0+64}
    const float* ah = Ah + rg * 4 * DIM;
    const float* ax = Ax + rg * 4 * DIM;

    float aih[3][4][2] = {};
    float ahh[3][4][2] = {};

    for (int k = 0; k < 128; k += 4) {
        float4 h0 = *(const float4*)(ah + 0 * DIM + k);
        float4 h1 = *(const float4*)(ah + 1 * DIM + k);
        float4 h2 = *(const float4*)(ah + 2 * DIM + k);
        float4 h3 = *(const float4*)(ah + 3 * DIM + k);
        float4 x0 = *(const float4*)(ax + 0 * DIM + k);
        float4 x1 = *(const float4*)(ax + 1 * DIM + k);
        float4 x2 = *(const float4*)(ax + 2 * DIM + k);
        float4 x3 = *(const float4*)(ax + 3 * DIM + k);
        #pragma unroll
        for (int g = 0; g < 3; ++g) {
            const float* wi = Wih + (size_t)(g * 128 + c0) * 128 + k;
            const float* wh = Whh + (size_t)(g * 128 + c0) * 128 + k;
            float4 wi0 = *(const float4*)wi;
            float4 wi1 = *(const float4*)(wi + 64 * 128);
            float4 wh0 = *(const float4*)wh;
            float4 wh1 = *(const float4*)(wh + 64 * 128);
            #pragma unroll
            for (int kk = 0; kk < 4; ++kk) {
                float a, b0, b1;
                b0 = F4(wi0, kk); b1 = F4(wi1, kk);
                a = F4(h0, kk); aih[g][0][0] += a * b0; aih[g][0][1] += a * b1;
                a = F4(h1, kk); aih[g][1][0] += a * b0; aih[g][1][1] += a * b1;
                a = F4(h2, kk); aih[g][2][0] += a * b0; aih[g][2][1] += a * b1;
                a = F4(h3, kk); aih[g][3][0] += a * b0; aih[g][3][1] += a * b1;
                b0 = F4(wh0, kk); b1 = F4(wh1, kk);
                a = F4(x0, kk); ahh[g][0][0] += a * b0; ahh[g][0][1] += a * b1;
                a = F4(x1, kk); ahh[g][1][0] += a * b0; ahh[g][1][1] += a * b1;
                a = F4(x2, kk); ahh[g][2][0] += a * b0; ahh[g][2][1] += a * b1;
                a = F4(x3, kk); ahh[g][3][0] += a * b0; ahh[g][3][1] += a * b1;
            }
        }
    }

    #pragma unroll
    for (int r = 0; r < 4; ++r) {
        int row = r0 + rg * 4 + r;
        if (row >= n) continue;
        #pragma unroll
        for (int cs = 0; cs < 2; ++cs) {
            int j = c0 + cs * 64;
            float ir = aih[0][r][cs] + bih[j];
            float iz = aih[1][r][cs] + bih[128 + j];
            float in_ = aih[2][r][cs] + bih[256 + j];
            float hr = ahh[0][r][cs] + bhh[j];
            float hz = ahh[1][r][cs] + bhh[128 + j];
            float hn = ahh[2][r][cs] + bhh[256 + j];
            float rr = 1.f / (1.f + __expf(-(ir + hr)));
            float zz = 1.f / (1.f + __expf(-(iz + hz)));
            float nn = tanhf(in_ + rr * hn);
            float hp = ax[r * DIM + j];
            Out[(size_t)row * DIM + j] = (1.f - zz) * nn + zz * hp;
        }
    }
}

// ---------------- host launch ----------------

extern "C" void kernel_launch(void* const* d_in, const int* in_sizes, int n_in,
                              void* d_out, int out_size, void* d_ws, size_t ws_size,
                              hipStream_t stream) {
    const float* x     = (const float*)d_in[0];
    const int*   ei    = (const int*)d_in[1];
    const float* xprev = (const float*)d_in[2];
    const float* W     = (const float*)d_in[3];
    const float* b     = (const float*)d_in[4];
    const float* Wih   = (const float*)d_in[5];
    const float* Whh   = (const float*)d_in[6];
    const float* bih   = (const float*)d_in[7];
    const float* bhh   = (const float*)d_in[8];

    int N = in_sizes[0] / DIM;
    int E = in_sizes[1] / 2;
    const int* esrc = ei;
    const int* edst = ei + E;

    // workspace layout (~59 MB)
    char* p = (char*)d_ws;
    auto alloc = [&](size_t bytes) {
        char* q = p;
        p += (bytes + 255) & ~(size_t)255;
        return q;
    };
    float* dinv = (float*)alloc((size_t)N * 4);
    int*   cnt  = (int*)  alloc((size_t)N * 4);
    int*   rowp = (int*)  alloc((size_t)(N + 1) * 4);
    int*   fill = (int*)  alloc((size_t)N * 4);
    int*   srcs = (int*)  alloc((size_t)E * 4);
    float* xw   = (float*)alloc((size_t)N * DIM * 4);
    float* out  = (float*)d_out;

    k_zero  <<<(N + 255) / 256, 256, 0, stream>>>(cnt, N);
    k_degree<<<(E + 255) / 256, 256, 0, stream>>>(edst, cnt, E);
    k_dinv  <<<(N + 255) / 256, 256, 0, stream>>>(cnt, dinv, N);
    k_scan  <<<1, 1024, 0, stream>>>(cnt, rowp, fill, N);
    k_bucket<<<(E + 255) / 256, 256, 0, stream>>>(esrc, edst, fill, srcs, E);
    k_gemm1 <<<(N + 15) / 16, 256, 0, stream>>>(x, W, xw, N);
    k_gather<<<(N + 3) / 4, 256, 0, stream>>>(xw, dinv, rowp, srcs, b, out, N);
    k_gru   <<<(N + 15) / 16, 256, 0, stream>>>(out, xprev, Wih, Whh, bih, bhh, out, N);
}

// Round 2
// 678.496 us; speedup vs baseline: 3.6691x; 3.6691x over previous
//
#include <hip/hip_runtime.h>
#include <hip/hip_bf16.h>
#include <math.h>

#define DIM 128

typedef __attribute__((ext_vector_type(8))) short bf16x8;
typedef __attribute__((ext_vector_type(4))) float f32x4;
typedef unsigned short u16;
typedef unsigned int u32;

__device__ __forceinline__ u16 f2bf(float x) {
    u32 u = __builtin_bit_cast(u32, x);
    u += 0x7fff + ((u >> 16) & 1);          // RNE
    return (u16)(u >> 16);
}
__device__ __forceinline__ float bf2f(u16 h) {
    return __builtin_bit_cast(float, (u32)h << 16);
}

// ---------------- graph prep ----------------

__global__ __launch_bounds__(256) void k_zero(int* __restrict__ p, int n) {
    int i = blockIdx.x * 256 + threadIdx.x;
    if (i < n) p[i] = 0;
}

__global__ __launch_bounds__(256) void k_degree(const int* __restrict__ dst,
                                                int* __restrict__ cnt, int E) {
    int e = blockIdx.x * 256 + threadIdx.x;
    if (e < E) atomicAdd(&cnt[dst[e]], 1);
}

__global__ __launch_bounds__(256) void k_dinv(const int* __restrict__ cnt,
                                              float* __restrict__ dinv, int n) {
    int i = blockIdx.x * 256 + threadIdx.x;
    if (i < n) dinv[i] = rsqrtf((float)(cnt[i] + 1));  // +1 self loop
}

__global__ __launch_bounds__(1024) void k_scan(const int* __restrict__ cnt,
                                               int* __restrict__ row_ptr,
                                               int* __restrict__ fill, int n) {
    __shared__ int wsum[16];
    int t = threadIdx.x;
    int lane = t & 63, wid = t >> 6;
    int chunk = (((n + 1023) >> 10) + 3) & ~3;
    int start = t * chunk;
    int end = start + chunk; if (end > n) end = n;

    int s = 0;
    for (int i = start; i < end; ++i) s += cnt[i];

    int incl = s;
    #pragma unroll
    for (int off = 1; off < 64; off <<= 1) {
        int y = __shfl_up(incl, off, 64);
        if (lane >= off) incl += y;
    }
    if (lane == 63) wsum[wid] = incl;
    __syncthreads();
    if (t == 0) {
        int run = 0;
        #pragma unroll
        for (int w = 0; w < 16; ++w) { int v = wsum[w]; wsum[w] = run; run += v; }
    }
    __syncthreads();
    int excl = wsum[wid] + incl - s;

    int run = excl;
    for (int i = start; i < end; ++i) {
        row_ptr[i] = run;
        fill[i]    = run;
        run += cnt[i];
    }
    if (start < n && end == n) row_ptr[n] = run;
}

__global__ __launch_bounds__(256) void k_bucket(const int* __restrict__ src,
                                                const int* __restrict__ dst,
                                                int* __restrict__ fill,
                                                int* __restrict__ srcs, int E) {
    int e = blockIdx.x * 256 + threadIdx.x;
    if (e < E) {
        int d = dst[e];
        int pos = atomicAdd(&fill[d], 1);
        srcs[pos] = src[e];
    }
}

// ---------------- dtype prep ----------------

// Wt[c][k] = bf16(W[k][c]); Wih/Whh cast in place layout [out=3*128][k=128]
__global__ __launch_bounds__(256) void k_prepw(const float* __restrict__ W,
                                               const float* __restrict__ Wih,
                                               const float* __restrict__ Whh,
                                               u16* __restrict__ Wt,
                                               u16* __restrict__ Wihb,
                                               u16* __restrict__ Whhb) {
    int i = blockIdx.x * 256 + threadIdx.x;
    if (i < 128 * 128) {
        int k = i >> 7, c = i & 127;
        Wt[c * 128 + k] = f2bf(W[i]);
    }
    if (i < 3 * 128 * 128) {
        Wihb[i] = f2bf(Wih[i]);
        Whhb[i] = f2bf(Whh[i]);
    }
}

// cast two fp32 arrays to bf16 (X and x_prev)
__global__ __launch_bounds__(256) void k_cast2(const float4* __restrict__ a,
                                               const float4* __restrict__ b,
                                               u32* __restrict__ ab,
                                               u32* __restrict__ bb, int n4) {
    int stride = gridDim.x * 256;
    for (int i = blockIdx.x * 256 + threadIdx.x; i < n4; i += stride) {
        float4 v = a[i];
        ab[i * 2 + 0] = (u32)f2bf(v.x) | ((u32)f2bf(v.y) << 16);
        ab[i * 2 + 1] = (u32)f2bf(v.z) | ((u32)f2bf(v.w) << 16);
        float4 w = b[i];
        bb[i * 2 + 0] = (u32)f2bf(w.x) | ((u32)f2bf(w.y) << 16);
        bb[i * 2 + 1] = (u32)f2bf(w.z) | ((u32)f2bf(w.w) << 16);
    }
}

// ---------------- GEMM1: XW_bf = X_bf @ Wt_bf (MFMA) ----------------
// block: 256 thr = 4 waves, 32 rows; wave w covers cols [w*32, w*32+32)

__global__ __launch_bounds__(256) void k_gemm1(const u16* __restrict__ Xb,
                                               const u16* __restrict__ Wt,
                                               u16* __restrict__ XWb, int n) {
    int t = threadIdx.x, w = t >> 6, l = t & 63;
    int r0 = blockIdx.x * 32;
    int lr = l & 15;
    int kq = (l >> 4) * 8;

    f32x4 acc[2][2];  // [stripe][ctile]
    #pragma unroll
    for (int s = 0; s < 2; ++s)
        #pragma unroll
        for (int c = 0; c < 2; ++c) acc[s][c] = (f32x4){0.f, 0.f, 0.f, 0.f};

    #pragma unroll
    for (int kb = 0; kb < 4; ++kb) {
        int ko = kb * 32 + kq;
        bf16x8 a0 = *(const bf16x8*)(Xb + (size_t)(r0 + lr) * DIM + ko);
        bf16x8 a1 = *(const bf16x8*)(Xb + (size_t)(r0 + 16 + lr) * DIM + ko);
        bf16x8 b0 = *(const bf16x8*)(Wt + (w * 32 + lr) * DIM + ko);
        bf16x8 b1 = *(const bf16x8*)(Wt + (w * 32 + 16 + lr) * DIM + ko);
        acc[0][0] = __builtin_amdgcn_mfma_f32_16x16x32_bf16(a0, b0, acc[0][0], 0, 0, 0);
        acc[0][1] = __builtin_amdgcn_mfma_f32_16x16x32_bf16(a0, b1, acc[0][1], 0, 0, 0);
        acc[1][0] = __builtin_amdgcn_mfma_f32_16x16x32_bf16(a1, b0, acc[1][0], 0, 0, 0);
        acc[1][1] = __builtin_amdgcn_mfma_f32_16x16x32_bf16(a1, b1, acc[1][1], 0, 0, 0);
    }

    #pragma unroll
    for (int s = 0; s < 2; ++s)
        #pragma unroll
        for (int c = 0; c < 2; ++c)
            #pragma unroll
            for (int i = 0; i < 4; ++i) {
                int row = r0 + s * 16 + (l >> 4) * 4 + i;
                if (row < n) {
                    int col = w * 32 + c * 16 + lr;
                    XWb[(size_t)row * DIM + col] = f2bf(acc[s][c][i]);
                }
            }
}

// ---------------- gather (bf16 in/out) ----------------

__global__ __launch_bounds__(256) void k_gather(const u16* __restrict__ XWb,
                                                const float* __restrict__ dinv,
                                                const int* __restrict__ row_ptr,
                                                const int* __restrict__ srcs,
                                                const float* __restrict__ bias,
                                                u16* __restrict__ Hcb, int n) {
    int node = blockIdx.x * 4 + (threadIdx.x >> 6);
    if (node >= n) return;
    int lane = threadIdx.x & 63;
    int c = lane * 2;

    float di = dinv[node];
    u32 sv = *(const u32*)(XWb + (size_t)node * DIM + c);
    float accx = bias[c]     + bf2f((u16)(sv & 0xffff)) * di * di;
    float accy = bias[c + 1] + bf2f((u16)(sv >> 16))    * di * di;

    int e = row_ptr[node], end = row_ptr[node + 1];
    for (; e + 3 < end; e += 4) {
        int s0 = srcs[e], s1 = srcs[e + 1], s2 = srcs[e + 2], s3 = srcs[e + 3];
        float n0 = dinv[s0] * di, n1 = dinv[s1] * di, n2 = dinv[s2] * di, n3 = dinv[s3] * di;
        u32 v0 = *(const u32*)(XWb + (size_t)s0 * DIM + c);
        u32 v1 = *(const u32*)(XWb + (size_t)s1 * DIM + c);
        u32 v2 = *(const u32*)(XWb + (size_t)s2 * DIM + c);
        u32 v3 = *(const u32*)(XWb + (size_t)s3 * DIM + c);
        accx += bf2f((u16)(v0 & 0xffff)) * n0 + bf2f((u16)(v1 & 0xffff)) * n1
              + bf2f((u16)(v2 & 0xffff)) * n2 + bf2f((u16)(v3 & 0xffff)) * n3;
        accy += bf2f((u16)(v0 >> 16)) * n0 + bf2f((u16)(v1 >> 16)) * n1
              + bf2f((u16)(v2 >> 16)) * n2 + bf2f((u16)(v3 >> 16)) * n3;
    }
    for (; e < end; ++e) {
        int s = srcs[e];
        float nrm = dinv[s] * di;
        u32 v = *(const u32*)(XWb + (size_t)s * DIM + c);
        accx += bf2f((u16)(v & 0xffff)) * nrm;
        accy += bf2f((u16)(v >> 16)) * nrm;
    }
    *(u32*)(Hcb + (size_t)node * DIM + c) = (u32)f2bf(accx) | ((u32)f2bf(accy) << 16);
}

// ---------------- fused GRU (MFMA) ----------------
// block: 256 thr = 4 waves, 32 rows, all 768 gate cols.
// wave w: gate cols [w*32, w*32+32), tiles [gate 3][stripe 2][ctile 2] x {ih,hh}

__global__ __launch_bounds__(256) void k_gru(const u16* __restrict__ Hcb,
                                             const u16* __restrict__ Xpb,
                                             const u16* __restrict__ Wihb,
                                             const u16* __restrict__ Whhb,
                                             const float* __restrict__ bih,
                                             const float* __restrict__ bhh,
                                             const float* __restrict__ Xp,
                                             float* __restrict__ Out, int n) {
    int t = threadIdx.x, w = t >> 6, l = t & 63;
    int r0 = blockIdx.x * 32;
    int lr = l & 15;
    int kq = (l >> 4) * 8;

    f32x4 aI[3][2][2], aH[3][2][2];  // [gate][stripe][ctile]
    #pragma unroll
    for (int g = 0; g < 3; ++g)
        #pragma unroll
        for (int s = 0; s < 2; ++s)
            #pragma unroll
            for (int c = 0; c < 2; ++c) {
                aI[g][s][c] = (f32x4){0.f, 0.f, 0.f, 0.f};
                aH[g][s][c] = (f32x4){0.f, 0.f, 0.f, 0.f};
            }

    #pragma unroll
    for (int kb = 0; kb < 4; ++kb) {
        int ko = kb * 32 + kq;
        bf16x8 hA0 = *(const bf16x8*)(Hcb + (size_t)(r0 + lr) * DIM + ko);
        bf16x8 hA1 = *(const bf16x8*)(Hcb + (size_t)(r0 + 16 + lr) * DIM + ko);
        bf16x8 xA0 = *(const bf16x8*)(Xpb + (size_t)(r0 + lr) * DIM + ko);
        bf16x8 xA1 = *(const bf16x8*)(Xpb + (size_t)(r0 + 16 + lr) * DIM + ko);
        #pragma unroll
        for (int g = 0; g < 3; ++g)
            #pragma unroll
            for (int c = 0; c < 2; ++c) {
                int orow = g * 128 + w * 32 + c * 16 + lr;
                bf16x8 bI = *(const bf16x8*)(Wihb + (size_t)orow * DIM + ko);
                bf16x8 bH = *(const bf16x8*)(Whhb + (size_t)orow * DIM + ko);
                aI[g][0][c] = __builtin_amdgcn_mfma_f32_16x16x32_bf16(hA0, bI, aI[g][0][c], 0, 0, 0);
                aI[g][1][c] = __builtin_amdgcn_mfma_f32_16x16x32_bf16(hA1, bI, aI[g][1][c], 0, 0, 0);
                aH[g][0][c] = __builtin_amdgcn_mfma_f32_16x16x32_bf16(xA0, bH, aH[g][0][c], 0, 0, 0);
                aH[g][1][c] = __builtin_amdgcn_mfma_f32_16x16x32_bf16(xA1, bH, aH[g][1][c], 0, 0, 0);
            }
    }

    #pragma unroll
    for (int c = 0; c < 2; ++c) {
        int j = w * 32 + c * 16 + lr;
        float br = bih[j],        bz = bih[128 + j],  bn = bih[256 + j];
        float cr = bhh[j],        cz = bhh[128 + j],  cn = bhh[256 + j];
        #pragma unroll
        for (int s = 0; s < 2; ++s)
            #pragma unroll
            for (int i = 0; i < 4; ++i) {
                int row = r0 + s * 16 + (l >> 4) * 4 + i;
                if (row >= n) continue;
                float ir = aI[0][s][c][i] + br;
                float iz = aI[1][s][c][i] + bz;
                float in_ = aI[2][s][c][i] + bn;
                float hr = aH[0][s][c][i] + cr;
                float hz = aH[1][s][c][i] + cz;
                float hn = aH[2][s][c][i] + cn;
                float rr = 1.f / (1.f + __expf(-(ir + hr)));
                float zz = 1.f / (1.f + __expf(-(iz + hz)));
                float nn = tanhf(in_ + rr * hn);
                float hp = Xp[(size_t)row * DIM + j];
                Out[(size_t)row * DIM + j] = (1.f - zz) * nn + zz * hp;
            }
    }
}

// ---------------- host launch ----------------

extern "C" void kernel_launch(void* const* d_in, const int* in_sizes, int n_in,
                              void* d_out, int out_size, void* d_ws, size_t ws_size,
                              hipStream_t stream) {
    const float* x     = (const float*)d_in[0];
    const int*   ei    = (const int*)d_in[1];
    const float* xprev = (const float*)d_in[2];
    const float* W     = (const float*)d_in[3];
    const float* b     = (const float*)d_in[4];
    const float* Wih   = (const float*)d_in[5];
    const float* Whh   = (const float*)d_in[6];
    const float* bih   = (const float*)d_in[7];
    const float* bhh   = (const float*)d_in[8];

    int N = in_sizes[0] / DIM;
    int E = in_sizes[1] / 2;
    const int* esrc = ei;
    const int* edst = ei + E;

    char* p = (char*)d_ws;
    auto alloc = [&](size_t bytes) {
        char* q = p;
        p += (bytes + 255) & ~(size_t)255;
        return q;
    };
    float* dinv = (float*)alloc((size_t)N * 4);
    int*   cnt  = (int*)  alloc((size_t)N * 4);
    int*   rowp = (int*)  alloc((size_t)(N + 1) * 4);
    int*   fill = (int*)  alloc((size_t)N * 4);
    int*   srcs = (int*)  alloc((size_t)E * 4);
    u16*   Xb   = (u16*)  alloc((size_t)N * DIM * 2);   // later reused as Hcb
    u16*   Xpb  = (u16*)  alloc((size_t)N * DIM * 2);
    u16*   XWb  = (u16*)  alloc((size_t)N * DIM * 2);
    u16*   Wt   = (u16*)  alloc(128 * 128 * 2);
    u16*   Wihb = (u16*)  alloc(3 * 128 * 128 * 2);
    u16*   Whhb = (u16*)  alloc(3 * 128 * 128 * 2);
    u16*   Hcb  = Xb;  // X_bf dead after k_gemm1
    float* out  = (float*)d_out;

    k_zero  <<<(N + 255) / 256, 256, 0, stream>>>(cnt, N);
    k_degree<<<(E + 255) / 256, 256, 0, stream>>>(edst, cnt, E);
    k_dinv  <<<(N + 255) / 256, 256, 0, stream>>>(cnt, dinv, N);
    k_scan  <<<1, 1024, 0, stream>>>(cnt, rowp, fill, N);
    k_bucket<<<(E + 255) / 256, 256, 0, stream>>>(esrc, edst, fill, srcs, E);
    k_prepw <<<192, 256, 0, stream>>>(W, Wih, Whh, Wt, Wihb, Whhb);
    int n4 = N * DIM / 4;
    k_cast2 <<<2048, 256, 0, stream>>>((const float4*)x, (const float4*)xprev,
                                       (u32*)Xb, (u32*)Xpb, n4);
    k_gemm1 <<<(N + 31) / 32, 256, 0, stream>>>(Xb, Wt, XWb, N);
    k_gather<<<(N + 3) / 4, 256, 0, stream>>>(XWb, dinv, rowp, srcs, b, Hcb, N);
    k_gru   <<<(N + 31) / 32, 256, 0, stream>>>(Hcb, Xpb, Wihb, Whhb, bih, bhh,
                                                xprev, out, N);
}

// Round 3
// 462.224 us; speedup vs baseline: 5.3858x; 1.4679x over previous
//
#include <hip/hip_runtime.h>
#include <hip/hip_bf16.h>
#include <math.h>

#define DIM 128

typedef __attribute__((ext_vector_type(8))) short bf16x8;
typedef __attribute__((ext_vector_type(4))) float f32x4;
typedef unsigned short u16;
typedef unsigned int u32;

__device__ __forceinline__ u16 f2bf(float x) {
    u32 u = __builtin_bit_cast(u32, x);
    u += 0x7fff + ((u >> 16) & 1);          // RNE
    return (u16)(u >> 16);
}
__device__ __forceinline__ float bf2f(u16 h) {
    return __builtin_bit_cast(float, (u32)h << 16);
}

// ---------------- graph prep ----------------

__global__ __launch_bounds__(256) void k_zero(int* __restrict__ p, int n) {
    int i = blockIdx.x * 256 + threadIdx.x;
    if (i < n) p[i] = 0;
}

__global__ __launch_bounds__(256) void k_degree(const int* __restrict__ dst,
                                                int* __restrict__ cnt, int E) {
    int e = blockIdx.x * 256 + threadIdx.x;
    if (e < E) atomicAdd(&cnt[dst[e]], 1);
}

__global__ __launch_bounds__(256) void k_dinv(const int* __restrict__ cnt,
                                              float* __restrict__ dinv, int n) {
    int i = blockIdx.x * 256 + threadIdx.x;
    if (i < n) dinv[i] = rsqrtf((float)(cnt[i] + 1));  // +1 self loop
}

// ---- hierarchical exclusive scan: 1024 elems per block ----

__global__ __launch_bounds__(256) void k_scan1(const int* __restrict__ cnt,
                                               int* __restrict__ bsum, int n) {
    int b = blockIdx.x, t = threadIdx.x;
    int base = b * 1024 + t * 4;
    int s = 0;
    #pragma unroll
    for (int j = 0; j < 4; ++j) {
        int i = base + j;
        if (i < n) s += cnt[i];
    }
    #pragma unroll
    for (int off = 32; off; off >>= 1) s += __shfl_down(s, off, 64);
    __shared__ int ws[4];
    if ((t & 63) == 0) ws[t >> 6] = s;
    __syncthreads();
    if (t == 0) bsum[b] = ws[0] + ws[1] + ws[2] + ws[3];
}

// single small block: exclusive scan of nb (<=256) block sums; writes total to row_ptr[n]
__global__ __launch_bounds__(256) void k_scan2(const int* __restrict__ bsum,
                                               int* __restrict__ boff,
                                               int* __restrict__ row_ptr,
                                               int nb, int n) {
    int t = threadIdx.x, lane = t & 63, wid = t >> 6;
    int v = (t < nb) ? bsum[t] : 0;
    int incl = v;
    #pragma unroll
    for (int off = 1; off < 64; off <<= 1) {
        int y = __shfl_up(incl, off, 64);
        if (lane >= off) incl += y;
    }
    __shared__ int ws[4];
    if (lane == 63) ws[wid] = incl;
    __syncthreads();
    int add = 0;
    for (int w = 0; w < wid; ++w) add += ws[w];
    incl += add;
    if (t < nb) boff[t] = incl - v;
    if (t == 255) row_ptr[n] = incl;  // grand total == E
}

__global__ __launch_bounds__(256) void k_scan3(const int* __restrict__ cnt,
                                               const int* __restrict__ boff,
                                               int* __restrict__ row_ptr,
                                               int* __restrict__ fill, int n) {
    int b = blockIdx.x, t = threadIdx.x, lane = t & 63, wid = t >> 6;
    int base = b * 1024 + t * 4;
    int c[4];
    int s = 0;
    #pragma unroll
    for (int j = 0; j < 4; ++j) {
        int i = base + j;
        c[j] = (i < n) ? cnt[i] : 0;
        s += c[j];
    }
    int incl = s;
    #pragma unroll
    for (int off = 1; off < 64; off <<= 1) {
        int y = __shfl_up(incl, off, 64);
        if (lane >= off) incl += y;
    }
    __shared__ int ws[4];
    if (lane == 63) ws[wid] = incl;
    __syncthreads();
    int add = 0;
    for (int w = 0; w < wid; ++w) add += ws[w];
    int run = boff[b] + add + (incl - s);   // exclusive prefix for this thread's 4
    #pragma unroll
    for (int j = 0; j < 4; ++j) {
        int i = base + j;
        if (i < n) {
            row_ptr[i] = run;
            fill[i]    = run;
            run += c[j];
        }
    }
}

__global__ __launch_bounds__(256) void k_bucket(const int* __restrict__ src,
                                                const int* __restrict__ dst,
                                                int* __restrict__ fill,
                                                int* __restrict__ srcs, int E) {
    int e = blockIdx.x * 256 + threadIdx.x;
    if (e < E) {
        int d = dst[e];
        int pos = atomicAdd(&fill[d], 1);
        srcs[pos] = src[e];
    }
}

// ---------------- dtype prep ----------------

// Wt[c][k] = bf16(W[k][c]); Wih/Whh cast, layout [out=3*128][k=128]
__global__ __launch_bounds__(256) void k_prepw(const float* __restrict__ W,
                                               const float* __restrict__ Wih,
                                               const float* __restrict__ Whh,
                                               u16* __restrict__ Wt,
                                               u16* __restrict__ Wihb,
                                               u16* __restrict__ Whhb) {
    int i = blockIdx.x * 256 + threadIdx.x;
    if (i < 128 * 128) {
        int k = i >> 7, c = i & 127;
        Wt[c * 128 + k] = f2bf(W[i]);
    }
    if (i < 3 * 128 * 128) {
        Wihb[i] = f2bf(Wih[i]);
        Whhb[i] = f2bf(Whh[i]);
    }
}

// cast x_prev to bf16
__global__ __launch_bounds__(256) void k_cast1(const float4* __restrict__ a,
                                               u32* __restrict__ ab, int n4) {
    int stride = gridDim.x * 256;
    for (int i = blockIdx.x * 256 + threadIdx.x; i < n4; i += stride) {
        float4 v = a[i];
        ab[i * 2 + 0] = (u32)f2bf(v.x) | ((u32)f2bf(v.y) << 16);
        ab[i * 2 + 1] = (u32)f2bf(v.z) | ((u32)f2bf(v.w) << 16);
    }
}

// ---------------- GEMM1: XW_bf = bf16(X) @ Wt_bf (MFMA, fused cast) -----
// block: 256 thr = 4 waves, 32 rows; wave w covers cols [w*32, w*32+32)

__global__ __launch_bounds__(256) void k_gemm1(const float* __restrict__ X,
                                               const u16* __restrict__ Wt,
                                               u16* __restrict__ XWb, int n) {
    int t = threadIdx.x, w = t >> 6, l = t & 63;
    int r0 = blockIdx.x * 32;
    int lr = l & 15;
    int kq = (l >> 4) * 8;

    f32x4 acc[2][2];
    #pragma unroll
    for (int s = 0; s < 2; ++s)
        #pragma unroll
        for (int c = 0; c < 2; ++c) acc[s][c] = (f32x4){0.f, 0.f, 0.f, 0.f};

    #pragma unroll
    for (int kb = 0; kb < 4; ++kb) {
        int ko = kb * 32 + kq;
        const float* xr0 = X + (size_t)(r0 + lr) * DIM + ko;
        const float* xr1 = X + (size_t)(r0 + 16 + lr) * DIM + ko;
        float4 f00 = *(const float4*)xr0, f01 = *(const float4*)(xr0 + 4);
        float4 f10 = *(const float4*)xr1, f11 = *(const float4*)(xr1 + 4);
        bf16x8 a0, a1;
        a0[0] = (short)f2bf(f00.x); a0[1] = (short)f2bf(f00.y);
        a0[2] = (short)f2bf(f00.z); a0[3] = (short)f2bf(f00.w);
        a0[4] = (short)f2bf(f01.x); a0[5] = (short)f2bf(f01.y);
        a0[6] = (short)f2bf(f01.z); a0[7] = (short)f2bf(f01.w);
        a1[0] = (short)f2bf(f10.x); a1[1] = (short)f2bf(f10.y);
        a1[2] = (short)f2bf(f10.z); a1[3] = (short)f2bf(f10.w);
        a1[4] = (short)f2bf(f11.x); a1[5] = (short)f2bf(f11.y);
        a1[6] = (short)f2bf(f11.z); a1[7] = (short)f2bf(f11.w);
        bf16x8 b0 = *(const bf16x8*)(Wt + (w * 32 + lr) * DIM + ko);
        bf16x8 b1 = *(const bf16x8*)(Wt + (w * 32 + 16 + lr) * DIM + ko);
        acc[0][0] = __builtin_amdgcn_mfma_f32_16x16x32_bf16(a0, b0, acc[0][0], 0, 0, 0);
        acc[0][1] = __builtin_amdgcn_mfma_f32_16x16x32_bf16(a0, b1, acc[0][1], 0, 0, 0);
        acc[1][0] = __builtin_amdgcn_mfma_f32_16x16x32_bf16(a1, b0, acc[1][0], 0, 0, 0);
        acc[1][1] = __builtin_amdgcn_mfma_f32_16x16x32_bf16(a1, b1, acc[1][1], 0, 0, 0);
    }

    #pragma unroll
    for (int s = 0; s < 2; ++s)
        #pragma unroll
        for (int c = 0; c < 2; ++c)
            #pragma unroll
            for (int i = 0; i < 4; ++i) {
                int row = r0 + s * 16 + (l >> 4) * 4 + i;
                if (row < n) {
                    int col = w * 32 + c * 16 + lr;
                    XWb[(size_t)row * DIM + col] = f2bf(acc[s][c][i]);
                }
            }
}

// ---------------- gather (bf16 in/out) ----------------

__global__ __launch_bounds__(256) void k_gather(const u16* __restrict__ XWb,
                                                const float* __restrict__ dinv,
                                                const int* __restrict__ row_ptr,
                                                const int* __restrict__ srcs,
                                                const float* __restrict__ bias,
                                                u16* __restrict__ Hcb, int n) {
    int node = blockIdx.x * 4 + (threadIdx.x >> 6);
    if (node >= n) return;
    int lane = threadIdx.x & 63;
    int c = lane * 2;

    float di = dinv[node];
    u32 sv = *(const u32*)(XWb + (size_t)node * DIM + c);
    float accx = bias[c]     + bf2f((u16)(sv & 0xffff)) * di * di;
    float accy = bias[c + 1] + bf2f((u16)(sv >> 16))    * di * di;

    int e = row_ptr[node], end = row_ptr[node + 1];
    for (; e + 3 < end; e += 4) {
        int s0 = srcs[e], s1 = srcs[e + 1], s2 = srcs[e + 2], s3 = srcs[e + 3];
        float n0 = dinv[s0] * di, n1 = dinv[s1] * di, n2 = dinv[s2] * di, n3 = dinv[s3] * di;
        u32 v0 = *(const u32*)(XWb + (size_t)s0 * DIM + c);
        u32 v1 = *(const u32*)(XWb + (size_t)s1 * DIM + c);
        u32 v2 = *(const u32*)(XWb + (size_t)s2 * DIM + c);
        u32 v3 = *(const u32*)(XWb + (size_t)s3 * DIM + c);
        accx += bf2f((u16)(v0 & 0xffff)) * n0 + bf2f((u16)(v1 & 0xffff)) * n1
              + bf2f((u16)(v2 & 0xffff)) * n2 + bf2f((u16)(v3 & 0xffff)) * n3;
        accy += bf2f((u16)(v0 >> 16)) * n0 + bf2f((u16)(v1 >> 16)) * n1
              + bf2f((u16)(v2 >> 16)) * n2 + bf2f((u16)(v3 >> 16)) * n3;
    }
    for (; e < end; ++e) {
        int s = srcs[e];
        float nrm = dinv[s] * di;
        u32 v = *(const u32*)(XWb + (size_t)s * DIM + c);
        accx += bf2f((u16)(v & 0xffff)) * nrm;
        accy += bf2f((u16)(v >> 16)) * nrm;
    }
    *(u32*)(Hcb + (size_t)node * DIM + c) = (u32)f2bf(accx) | ((u32)f2bf(accy) << 16);
}

// ---------------- fused GRU (MFMA) ----------------
// block: 256 thr = 4 waves, 32 rows, all 768 gate cols.
// wave w: gate cols [w*32, w*32+32)

__global__ __launch_bounds__(256) void k_gru(const u16* __restrict__ Hcb,
                                             const u16* __restrict__ Xpb,
                                             const u16* __restrict__ Wihb,
                                             const u16* __restrict__ Whhb,
                                             const float* __restrict__ bih,
                                             const float* __restrict__ bhh,
                                             float* __restrict__ Out, int n) {
    int t = threadIdx.x, w = t >> 6, l = t & 63;
    int r0 = blockIdx.x * 32;
    int lr = l & 15;
    int kq = (l >> 4) * 8;

    f32x4 aI[3][2][2], aH[3][2][2];  // [gate][stripe][ctile]
    #pragma unroll
    for (int g = 0; g < 3; ++g)
        #pragma unroll
        for (int s = 0; s < 2; ++s)
            #pragma unroll
            for (int c = 0; c < 2; ++c) {
                aI[g][s][c] = (f32x4){0.f, 0.f, 0.f, 0.f};
                aH[g][s][c] = (f32x4){0.f, 0.f, 0.f, 0.f};
            }

    #pragma unroll
    for (int kb = 0; kb < 4; ++kb) {
        int ko = kb * 32 + kq;
        bf16x8 hA0 = *(const bf16x8*)(Hcb + (size_t)(r0 + lr) * DIM + ko);
        bf16x8 hA1 = *(const bf16x8*)(Hcb + (size_t)(r0 + 16 + lr) * DIM + ko);
        bf16x8 xA0 = *(const bf16x8*)(Xpb + (size_t)(r0 + lr) * DIM + ko);
        bf16x8 xA1 = *(const bf16x8*)(Xpb + (size_t)(r0 + 16 + lr) * DIM + ko);
        #pragma unroll
        for (int g = 0; g < 3; ++g)
            #pragma unroll
            for (int c = 0; c < 2; ++c) {
                int orow = g * 128 + w * 32 + c * 16 + lr;
                bf16x8 bI = *(const bf16x8*)(Wihb + (size_t)orow * DIM + ko);
                bf16x8 bH = *(const bf16x8*)(Whhb + (size_t)orow * DIM + ko);
                aI[g][0][c] = __builtin_amdgcn_mfma_f32_16x16x32_bf16(hA0, bI, aI[g][0][c], 0, 0, 0);
                aI[g][1][c] = __builtin_amdgcn_mfma_f32_16x16x32_bf16(hA1, bI, aI[g][1][c], 0, 0, 0);
                aH[g][0][c] = __builtin_amdgcn_mfma_f32_16x16x32_bf16(xA0, bH, aH[g][0][c], 0, 0, 0);
                aH[g][1][c] = __builtin_amdgcn_mfma_f32_16x16x32_bf16(xA1, bH, aH[g][1][c], 0, 0, 0);
            }
    }

    #pragma unroll
    for (int c = 0; c < 2; ++c) {
        int j = w * 32 + c * 16 + lr;
        float br = bih[j],        bz = bih[128 + j],  bn = bih[256 + j];
        float cr = bhh[j],        cz = bhh[128 + j],  cn = bhh[256 + j];
        #pragma unroll
        for (int s = 0; s < 2; ++s)
            #pragma unroll
            for (int i = 0; i < 4; ++i) {
                int row = r0 + s * 16 + (l >> 4) * 4 + i;
                if (row >= n) continue;
                float ir = aI[0][s][c][i] + br;
                float iz = aI[1][s][c][i] + bz;
                float in_ = aI[2][s][c][i] + bn;
                float hr = aH[0][s][c][i] + cr;
                float hz = aH[1][s][c][i] + cz;
                float hn = aH[2][s][c][i] + cn;
                float rr = 1.f / (1.f + __expf(-(ir + hr)));
                float zz = 1.f / (1.f + __expf(-(iz + hz)));
                float nn = tanhf(in_ + rr * hn);
                float hp = bf2f((u16)Xpb[(size_t)row * DIM + j]);
                Out[(size_t)row * DIM + j] = (1.f - zz) * nn + zz * hp;
            }
    }
}

// ---------------- host launch ----------------

extern "C" void kernel_launch(void* const* d_in, const int* in_sizes, int n_in,
                              void* d_out, int out_size, void* d_ws, size_t ws_size,
                              hipStream_t stream) {
    const float* x     = (const float*)d_in[0];
    const int*   ei    = (const int*)d_in[1];
    const float* xprev = (const float*)d_in[2];
    const float* W     = (const float*)d_in[3];
    const float* b     = (const float*)d_in[4];
    const float* Wih   = (const float*)d_in[5];
    const float* Whh   = (const float*)d_in[6];
    const float* bih   = (const float*)d_in[7];
    const float* bhh   = (const float*)d_in[8];

    int N = in_sizes[0] / DIM;
    int E = in_sizes[1] / 2;
    const int* esrc = ei;
    const int* edst = ei + E;

    char* p = (char*)d_ws;
    auto alloc = [&](size_t bytes) {
        char* q = p;
        p += (bytes + 255) & ~(size_t)255;
        return q;
    };
    float* dinv = (float*)alloc((size_t)N * 4);
    int*   cnt  = (int*)  alloc((size_t)N * 4);
    int*   rowp = (int*)  alloc((size_t)(N + 1) * 4);
    int*   fill = (int*)  alloc((size_t)N * 4);
    int*   srcs = (int*)  alloc((size_t)E * 4);
    u16*   Hcb  = (u16*)  alloc((size_t)N * DIM * 2);
    u16*   Xpb  = (u16*)  alloc((size_t)N * DIM * 2);
    u16*   XWb  = (u16*)  alloc((size_t)N * DIM * 2);
    u16*   Wt   = (u16*)  alloc(128 * 128 * 2);
    u16*   Wihb = (u16*)  alloc(3 * 128 * 128 * 2);
    u16*   Whhb = (u16*)  alloc(3 * 128 * 128 * 2);
    int    nb   = (N + 1023) / 1024;
    int*   bsum = (int*)  alloc((size_t)nb * 4);
    int*   boff = (int*)  alloc((size_t)nb * 4);
    float* out  = (float*)d_out;

    k_zero  <<<(N + 255) / 256, 256, 0, stream>>>(cnt, N);
    k_degree<<<(E + 255) / 256, 256, 0, stream>>>(edst, cnt, E);
    k_dinv  <<<(N + 255) / 256, 256, 0, stream>>>(cnt, dinv, N);
    k_scan1 <<<nb, 256, 0, stream>>>(cnt, bsum, N);
    k_scan2 <<<1, 256, 0, stream>>>(bsum, boff, rowp, nb, N);
    k_scan3 <<<nb, 256, 0, stream>>>(cnt, boff, rowp, fill, N);
    k_bucket<<<(E + 255) / 256, 256, 0, stream>>>(esrc, edst, fill, srcs, E);
    k_prepw <<<192, 256, 0, stream>>>(W, Wih, Whh, Wt, Wihb, Whhb);
    int n4 = N * DIM / 4;
    k_cast1 <<<2048, 256, 0, stream>>>((const float4*)xprev, (u32*)Xpb, n4);
    k_gemm1 <<<(N + 31) / 32, 256, 0, stream>>>(x, Wt, XWb, N);
    k_gather<<<(N + 3) / 4, 256, 0, stream>>>(XWb, dinv, rowp, srcs, b, Hcb, N);
    k_gru   <<<(N + 31) / 32, 256, 0, stream>>>(Hcb, Xpb, Wihb, Whhb, bih, bhh,
                                                out, N);
}

// Round 4
// 411.947 us; speedup vs baseline: 6.0432x; 1.1220x over previous
//
#include <hip/hip_runtime.h>
#include <hip/hip_bf16.h>
#include <math.h>

#define DIM 128

typedef __attribute__((ext_vector_type(8))) short bf16x8;
typedef __attribute__((ext_vector_type(4))) float f32x4;
typedef unsigned short u16;
typedef unsigned int u32;

__device__ __forceinline__ u16 f2bf(float x) {
    u32 u = __builtin_bit_cast(u32, x);
    u += 0x7fff + ((u >> 16) & 1);          // RNE
    return (u16)(u >> 16);
}
__device__ __forceinline__ float bf2f(u16 h) {
    return __builtin_bit_cast(float, (u32)h << 16);
}

// ---------------- graph prep ----------------

__global__ __launch_bounds__(256) void k_zero(int* __restrict__ p, int n) {
    int i = blockIdx.x * 256 + threadIdx.x;
    if (i < n) p[i] = 0;
}

__global__ __launch_bounds__(256) void k_degree(const int* __restrict__ dst,
                                                int* __restrict__ cnt, int E) {
    int e = blockIdx.x * 256 + threadIdx.x;
    if (e < E) atomicAdd(&cnt[dst[e]], 1);
}

__global__ __launch_bounds__(256) void k_dinv(const int* __restrict__ cnt,
                                              float* __restrict__ dinv, int n) {
    int i = blockIdx.x * 256 + threadIdx.x;
    if (i < n) dinv[i] = rsqrtf((float)(cnt[i] + 1));  // +1 self loop
}

// ---- hierarchical exclusive scan: 1024 elems per block ----

__global__ __launch_bounds__(256) void k_scan1(const int* __restrict__ cnt,
                                               int* __restrict__ bsum, int n) {
    int b = blockIdx.x, t = threadIdx.x;
    int base = b * 1024 + t * 4;
    int s = 0;
    #pragma unroll
    for (int j = 0; j < 4; ++j) {
        int i = base + j;
        if (i < n) s += cnt[i];
    }
    #pragma unroll
    for (int off = 32; off; off >>= 1) s += __shfl_down(s, off, 64);
    __shared__ int ws[4];
    if ((t & 63) == 0) ws[t >> 6] = s;
    __syncthreads();
    if (t == 0) bsum[b] = ws[0] + ws[1] + ws[2] + ws[3];
}

__global__ __launch_bounds__(256) void k_scan2(const int* __restrict__ bsum,
                                               int* __restrict__ boff,
                                               int* __restrict__ row_ptr,
                                               int nb, int n) {
    int t = threadIdx.x, lane = t & 63, wid = t >> 6;
    int v = (t < nb) ? bsum[t] : 0;
    int incl = v;
    #pragma unroll
    for (int off = 1; off < 64; off <<= 1) {
        int y = __shfl_up(incl, off, 64);
        if (lane >= off) incl += y;
    }
    __shared__ int ws[4];
    if (lane == 63) ws[wid] = incl;
    __syncthreads();
    int add = 0;
    for (int w = 0; w < wid; ++w) add += ws[w];
    incl += add;
    if (t < nb) boff[t] = incl - v;
    if (t == 255) row_ptr[n] = incl;  // grand total == E
}

__global__ __launch_bounds__(256) void k_scan3(const int* __restrict__ cnt,
                                               const int* __restrict__ boff,
                                               int* __restrict__ row_ptr,
                                               int* __restrict__ fill, int n) {
    int b = blockIdx.x, t = threadIdx.x, lane = t & 63, wid = t >> 6;
    int base = b * 1024 + t * 4;
    int c[4];
    int s = 0;
    #pragma unroll
    for (int j = 0; j < 4; ++j) {
        int i = base + j;
        c[j] = (i < n) ? cnt[i] : 0;
        s += c[j];
    }
    int incl = s;
    #pragma unroll
    for (int off = 1; off < 64; off <<= 1) {
        int y = __shfl_up(incl, off, 64);
        if (lane >= off) incl += y;
    }
    __shared__ int ws[4];
    if (lane == 63) ws[wid] = incl;
    __syncthreads();
    int add = 0;
    for (int w = 0; w < wid; ++w) add += ws[w];
    int run = boff[b] + add + (incl - s);
    #pragma unroll
    for (int j = 0; j < 4; ++j) {
        int i = base + j;
        if (i < n) {
            row_ptr[i] = run;
            fill[i]    = run;
            run += c[j];
        }
    }
}

__global__ __launch_bounds__(256) void k_bucket(const int* __restrict__ src,
                                                const int* __restrict__ dst,
                                                int* __restrict__ fill,
                                                int* __restrict__ srcs, int E) {
    int e = blockIdx.x * 256 + threadIdx.x;
    if (e < E) {
        int d = dst[e];
        int pos = atomicAdd(&fill[d], 1);
        srcs[pos] = src[e];
    }
}

// ---------------- dtype prep ----------------

__global__ __launch_bounds__(256) void k_prepw(const float* __restrict__ W,
                                               const float* __restrict__ Wih,
                                               const float* __restrict__ Whh,
                                               u16* __restrict__ Wt,
                                               u16* __restrict__ Wihb,
                                               u16* __restrict__ Whhb) {
    int i = blockIdx.x * 256 + threadIdx.x;
    if (i < 128 * 128) {
        int k = i >> 7, c = i & 127;
        Wt[c * 128 + k] = f2bf(W[i]);
    }
    if (i < 3 * 128 * 128) {
        Wihb[i] = f2bf(Wih[i]);
        Whhb[i] = f2bf(Whh[i]);
    }
}

__global__ __launch_bounds__(256) void k_cast1(const float4* __restrict__ a,
                                               u32* __restrict__ ab, int n4) {
    int stride = gridDim.x * 256;
    for (int i = blockIdx.x * 256 + threadIdx.x; i < n4; i += stride) {
        float4 v = a[i];
        ab[i * 2 + 0] = (u32)f2bf(v.x) | ((u32)f2bf(v.y) << 16);
        ab[i * 2 + 1] = (u32)f2bf(v.z) | ((u32)f2bf(v.w) << 16);
    }
}

// ---------------- GEMM1: XW_bf = bf16(X) @ Wt_bf (MFMA, W in LDS) ------
// block: 4 waves, 128 rows; wave w = rows [r0+w*32, +32), all 128 cols.

__global__ __launch_bounds__(256) void k_gemm1(const float* __restrict__ X,
                                               const u16* __restrict__ Wt,
                                               u16* __restrict__ XWb, int n) {
    __shared__ u16 Wlds[128 * 128];   // 32 KB, XOR-swizzled rows
    int t = threadIdx.x, w = t >> 6, l = t & 63;
    int lr = l & 15, q = l >> 4;

    for (int cidx = t; cidx < 2048; cidx += 256) {
        int r = cidx >> 4, kc = cidx & 15;
        int dst = r * 128 + ((kc * 8) ^ ((r & 7) << 3));
        *(bf16x8*)(Wlds + dst) = *(const bf16x8*)(Wt + r * 128 + kc * 8);
    }
    __syncthreads();

    int r0 = blockIdx.x * 128;
    int wrow0 = r0 + w * 32;
    int sw = (lr & 7) << 3;
    int ar0 = wrow0 + lr;      if (ar0 > n - 1) ar0 = n - 1;   // clamp: X sized exactly
    int ar1 = wrow0 + 16 + lr; if (ar1 > n - 1) ar1 = n - 1;
    const float* x0 = X + (size_t)ar0 * DIM;
    const float* x1 = X + (size_t)ar1 * DIM;

    f32x4 acc[2][8];
    #pragma unroll
    for (int s = 0; s < 2; ++s)
        #pragma unroll
        for (int c = 0; c < 8; ++c) acc[s][c] = (f32x4){0.f, 0.f, 0.f, 0.f};

    #pragma unroll
    for (int kb = 0; kb < 4; ++kb) {
        int ko = kb * 32 + q * 8;
        float4 f00 = *(const float4*)(x0 + ko), f01 = *(const float4*)(x0 + ko + 4);
        float4 f10 = *(const float4*)(x1 + ko), f11 = *(const float4*)(x1 + ko + 4);
        bf16x8 a0, a1;
        a0[0] = (short)f2bf(f00.x); a0[1] = (short)f2bf(f00.y);
        a0[2] = (short)f2bf(f00.z); a0[3] = (short)f2bf(f00.w);
        a0[4] = (short)f2bf(f01.x); a0[5] = (short)f2bf(f01.y);
        a0[6] = (short)f2bf(f01.z); a0[7] = (short)f2bf(f01.w);
        a1[0] = (short)f2bf(f10.x); a1[1] = (short)f2bf(f10.y);
        a1[2] = (short)f2bf(f10.z); a1[3] = (short)f2bf(f10.w);
        a1[4] = (short)f2bf(f11.x); a1[5] = (short)f2bf(f11.y);
        a1[6] = (short)f2bf(f11.z); a1[7] = (short)f2bf(f11.w);
        int kw = ko ^ sw;
        #pragma unroll
        for (int ct = 0; ct < 8; ++ct) {
            bf16x8 b = *(const bf16x8*)(Wlds + (ct * 16 + lr) * 128 + kw);
            acc[0][ct] = __builtin_amdgcn_mfma_f32_16x16x32_bf16(a0, b, acc[0][ct], 0, 0, 0);
            acc[1][ct] = __builtin_amdgcn_mfma_f32_16x16x32_bf16(a1, b, acc[1][ct], 0, 0, 0);
        }
    }

    #pragma unroll
    for (int s = 0; s < 2; ++s)
        #pragma unroll
        for (int ct = 0; ct < 8; ++ct)
            #pragma unroll
            for (int i = 0; i < 4; ++i) {
                int row = wrow0 + s * 16 + q * 4 + i;
                if (row < n)
                    XWb[(size_t)row * DIM + ct * 16 + lr] = f2bf(acc[s][ct][i]);
            }
}

// ---------------- gather (bf16 in/out) ----------------

__global__ __launch_bounds__(256) void k_gather(const u16* __restrict__ XWb,
                                                const float* __restrict__ dinv,
                                                const int* __restrict__ row_ptr,
                                                const int* __restrict__ srcs,
                                                const float* __restrict__ bias,
                                                u16* __restrict__ Hcb, int n) {
    int node = blockIdx.x * 4 + (threadIdx.x >> 6);
    if (node >= n) return;
    int lane = threadIdx.x & 63;
    int c = lane * 2;

    float di = dinv[node];
    u32 sv = *(const u32*)(XWb + (size_t)node * DIM + c);
    float accx = bias[c]     + bf2f((u16)(sv & 0xffff)) * di * di;
    float accy = bias[c + 1] + bf2f((u16)(sv >> 16))    * di * di;

    int e = row_ptr[node], end = row_ptr[node + 1];
    for (; e + 3 < end; e += 4) {
        int s0 = srcs[e], s1 = srcs[e + 1], s2 = srcs[e + 2], s3 = srcs[e + 3];
        float n0 = dinv[s0] * di, n1 = dinv[s1] * di, n2 = dinv[s2] * di, n3 = dinv[s3] * di;
        u32 v0 = *(const u32*)(XWb + (size_t)s0 * DIM + c);
        u32 v1 = *(const u32*)(XWb + (size_t)s1 * DIM + c);
        u32 v2 = *(const u32*)(XWb + (size_t)s2 * DIM + c);
        u32 v3 = *(const u32*)(XWb + (size_t)s3 * DIM + c);
        accx += bf2f((u16)(v0 & 0xffff)) * n0 + bf2f((u16)(v1 & 0xffff)) * n1
              + bf2f((u16)(v2 & 0xffff)) * n2 + bf2f((u16)(v3 & 0xffff)) * n3;
        accy += bf2f((u16)(v0 >> 16)) * n0 + bf2f((u16)(v1 >> 16)) * n1
              + bf2f((u16)(v2 >> 16)) * n2 + bf2f((u16)(v3 >> 16)) * n3;
    }
    for (; e < end; ++e) {
        int s = srcs[e];
        float nrm = dinv[s] * di;
        u32 v = *(const u32*)(XWb + (size_t)s * DIM + c);
        accx += bf2f((u16)(v & 0xffff)) * nrm;
        accy += bf2f((u16)(v >> 16)) * nrm;
    }
    *(u32*)(Hcb + (size_t)node * DIM + c) = (u32)f2bf(accx) | ((u32)f2bf(accy) << 16);
}

// ---------------- fused GRU (MFMA, weights in LDS) ----------------
// grid: (rowblocks*4); block = col-slice of 32 out-cols x 128 rows.
// LDS: 192 weight rows (3 gates x 32 cols x {ih,hh}) x 128 k, swizzled.

__global__ __launch_bounds__(256) void k_gru(const u16* __restrict__ Hcb,
                                             const u16* __restrict__ Xpb,
                                             const u16* __restrict__ Wihb,
                                             const u16* __restrict__ Whhb,
                                             const float* __restrict__ bih,
                                             const float* __restrict__ bhh,
                                             float* __restrict__ Out, int n) {
    __shared__ u16 Wlds[192 * 128];   // 48 KB
    int t = threadIdx.x, w = t >> 6, l = t & 63;
    int lr = l & 15, q = l >> 4;
    int cs = blockIdx.x & 3;
    int rb = blockIdx.x >> 2;
    int c0 = cs * 32;
    int r0 = rb * 128;

    for (int cidx = t; cidx < 3072; cidx += 256) {
        int r = cidx >> 4, kc = cidx & 15;
        int m = (r >= 96);
        int rr = m ? r - 96 : r;
        int g = rr >> 5, cc = rr & 31;
        const u16* src = (m ? Whhb : Wihb) + (size_t)((g << 7) + c0 + cc) * DIM + kc * 8;
        int dst = r * 128 + ((kc * 8) ^ ((r & 7) << 3));
        *(bf16x8*)(Wlds + dst) = *(const bf16x8*)src;
    }
    __syncthreads();

    int wrow0 = r0 + w * 32;
    int sw = (lr & 7) << 3;
    int ar0 = wrow0 + lr;      if (ar0 > n - 1) ar0 = n - 1;
    int ar1 = wrow0 + 16 + lr; if (ar1 > n - 1) ar1 = n - 1;
    const u16* hb0 = Hcb + (size_t)ar0 * DIM;
    const u16* hb1 = Hcb + (size_t)ar1 * DIM;
    const u16* xb0 = Xpb + (size_t)ar0 * DIM;
    const u16* xb1 = Xpb + (size_t)ar1 * DIM;

    f32x4 aI[3][2][2], aH[3][2][2];  // [gate][stripe][ctile]
    #pragma unroll
    for (int g = 0; g < 3; ++g)
        #pragma unroll
        for (int s = 0; s < 2; ++s)
            #pragma unroll
            for (int c = 0; c < 2; ++c) {
                aI[g][s][c] = (f32x4){0.f, 0.f, 0.f, 0.f};
                aH[g][s][c] = (f32x4){0.f, 0.f, 0.f, 0.f};
            }

    #pragma unroll
    for (int kb = 0; kb < 4; ++kb) {
        int ko = kb * 32 + q * 8;
        bf16x8 hA0 = *(const bf16x8*)(hb0 + ko);
        bf16x8 hA1 = *(const bf16x8*)(hb1 + ko);
        bf16x8 xA0 = *(const bf16x8*)(xb0 + ko);
        bf16x8 xA1 = *(const bf16x8*)(xb1 + ko);
        int kw = ko ^ sw;
        #pragma unroll
        for (int g = 0; g < 3; ++g)
            #pragma unroll
            for (int ct = 0; ct < 2; ++ct) {
                int ridx = (g * 32 + ct * 16 + lr) * 128 + kw;
                bf16x8 bI = *(const bf16x8*)(Wlds + ridx);
                bf16x8 bH = *(const bf16x8*)(Wlds + ridx + 96 * 128);
                aI[g][0][ct] = __builtin_amdgcn_mfma_f32_16x16x32_bf16(hA0, bI, aI[g][0][ct], 0, 0, 0);
                aI[g][1][ct] = __builtin_amdgcn_mfma_f32_16x16x32_bf16(hA1, bI, aI[g][1][ct], 0, 0, 0);
                aH[g][0][ct] = __builtin_amdgcn_mfma_f32_16x16x32_bf16(xA0, bH, aH[g][0][ct], 0, 0, 0);
                aH[g][1][ct] = __builtin_amdgcn_mfma_f32_16x16x32_bf16(xA1, bH, aH[g][1][ct], 0, 0, 0);
            }
    }

    #pragma unroll
    for (int ct = 0; ct < 2; ++ct) {
        int j = c0 + ct * 16 + lr;
        float br = bih[j],       bz = bih[128 + j], bn = bih[256 + j];
        float cr = bhh[j],       cz = bhh[128 + j], cn = bhh[256 + j];
        #pragma unroll
        for (int s = 0; s < 2; ++s)
            #pragma unroll
            for (int i = 0; i < 4; ++i) {
                int row = wrow0 + s * 16 + q * 4 + i;
                if (row >= n) continue;
                float ir = aI[0][s][ct][i] + br;
                float iz = aI[1][s][ct][i] + bz;
                float in_ = aI[2][s][ct][i] + bn;
                float hr = aH[0][s][ct][i] + cr;
                float hz = aH[1][s][ct][i] + cz;
                float hn = aH[2][s][ct][i] + cn;
                float rr = 1.f / (1.f + __expf(-(ir + hr)));
                float zz = 1.f / (1.f + __expf(-(iz + hz)));
                float nn = tanhf(in_ + rr * hn);
                float hp = bf2f((u16)Xpb[(size_t)row * DIM + j]);
                Out[(size_t)row * DIM + j] = (1.f - zz) * nn + zz * hp;
            }
    }
}

// ---------------- host launch ----------------

extern "C" void kernel_launch(void* const* d_in, const int* in_sizes, int n_in,
                              void* d_out, int out_size, void* d_ws, size_t ws_size,
                              hipStream_t stream) {
    const float* x     = (const float*)d_in[0];
    const int*   ei    = (const int*)d_in[1];
    const float* xprev = (const float*)d_in[2];
    const float* W     = (const float*)d_in[3];
    const float* b     = (const float*)d_in[4];
    const float* Wih   = (const float*)d_in[5];
    const float* Whh   = (const float*)d_in[6];
    const float* bih   = (const float*)d_in[7];
    const float* bhh   = (const float*)d_in[8];

    int N = in_sizes[0] / DIM;
    int E = in_sizes[1] / 2;
    const int* esrc = ei;
    const int* edst = ei + E;

    char* p = (char*)d_ws;
    auto alloc = [&](size_t bytes) {
        char* q = p;
        p += (bytes + 255) & ~(size_t)255;
        return q;
    };
    float* dinv = (float*)alloc((size_t)N * 4);
    int*   cnt  = (int*)  alloc((size_t)N * 4);
    int*   rowp = (int*)  alloc((size_t)(N + 1) * 4);
    int*   fill = (int*)  alloc((size_t)N * 4);
    int*   srcs = (int*)  alloc((size_t)E * 4);
    u16*   Hcb  = (u16*)  alloc((size_t)N * DIM * 2);
    u16*   Xpb  = (u16*)  alloc((size_t)N * DIM * 2);
    u16*   XWb  = (u16*)  alloc((size_t)N * DIM * 2);
    u16*   Wt   = (u16*)  alloc(128 * 128 * 2);
    u16*   Wihb = (u16*)  alloc(3 * 128 * 128 * 2);
    u16*   Whhb = (u16*)  alloc(3 * 128 * 128 * 2);
    int    nb   = (N + 1023) / 1024;
    int*   bsum = (int*)  alloc((size_t)nb * 4);
    int*   boff = (int*)  alloc((size_t)nb * 4);
    float* out  = (float*)d_out;

    k_zero  <<<(N + 255) / 256, 256, 0, stream>>>(cnt, N);
    k_degree<<<(E + 255) / 256, 256, 0, stream>>>(edst, cnt, E);
    k_dinv  <<<(N + 255) / 256, 256, 0, stream>>>(cnt, dinv, N);
    k_scan1 <<<nb, 256, 0, stream>>>(cnt, bsum, N);
    k_scan2 <<<1, 256, 0, stream>>>(bsum, boff, rowp, nb, N);
    k_scan3 <<<nb, 256, 0, stream>>>(cnt, boff, rowp, fill, N);
    k_bucket<<<(E + 255) / 256, 256, 0, stream>>>(esrc, edst, fill, srcs, E);
    k_prepw <<<192, 256, 0, stream>>>(W, Wih, Whh, Wt, Wihb, Whhb);
    int n4 = N * DIM / 4;
    k_cast1 <<<2048, 256, 0, stream>>>((const float4*)xprev, (u32*)Xpb, n4);
    int nrb = (N + 127) / 128;
    k_gemm1 <<<nrb, 256, 0, stream>>>(x, Wt, XWb, N);
    k_gather<<<(N + 3) / 4, 256, 0, stream>>>(XWb, dinv, rowp, srcs, b, Hcb, N);
    k_gru   <<<nrb * 4, 256, 0, stream>>>(Hcb, Xpb, Wihb, Whhb, bih, bhh, out, N);
}

// Round 5
// 310.749 us; speedup vs baseline: 8.0112x; 1.3257x over previous
//
#include <hip/hip_runtime.h>
#include <hip/hip_bf16.h>
#include <math.h>

#define DIM 128
#define PSHIFT 10          // 1024 nodes per partition
#define PSZ 1024
#define CHUNK 2048

typedef __attribute__((ext_vector_type(8))) short bf16x8;
typedef __attribute__((ext_vector_type(4))) float f32x4;
typedef unsigned short u16;
typedef unsigned int u32;
typedef unsigned long long u64;

__device__ __forceinline__ u16 f2bf(float x) {
    u32 u = __builtin_bit_cast(u32, x);
    u += 0x7fff + ((u >> 16) & 1);          // RNE
    return (u16)(u >> 16);
}
__device__ __forceinline__ float bf2f(u16 h) {
    return __builtin_bit_cast(float, (u32)h << 16);
}

// ---------------- partitioned CSR build ----------------

__global__ __launch_bounds__(256) void k_zero(int* __restrict__ p, int n) {
    int i = blockIdx.x * 256 + threadIdx.x;
    if (i < n) p[i] = 0;
}

// histogram edges into partitions (LDS-buffered)
__global__ __launch_bounds__(256) void k_pcount(const int* __restrict__ edst,
                                                int* __restrict__ pcnt, int E) {
    __shared__ int h[128];
    int t = threadIdx.x;
    if (t < 128) h[t] = 0;
    __syncthreads();
    int stride = gridDim.x * 256;
    for (int e = blockIdx.x * 256 + t; e < E; e += stride)
        atomicAdd(&h[edst[e] >> PSHIFT], 1);
    __syncthreads();
    if (t < 128 && h[t]) atomicAdd(&pcnt[t], h[t]);
}

// exclusive scan of P (<=128) partition counts
__global__ __launch_bounds__(256) void k_pscan(const int* __restrict__ pcnt,
                                               int* __restrict__ poff,
                                               int* __restrict__ pfill,
                                               int* __restrict__ rowp,
                                               int P, int N, int E) {
    __shared__ int a[256];
    int t = threadIdx.x;
    int v = (t < P) ? pcnt[t] : 0;
    a[t] = v;
    __syncthreads();
    #pragma unroll
    for (int off = 1; off < 256; off <<= 1) {
        int y = (t >= off) ? a[t - off] : 0;
        __syncthreads();
        a[t] += y;
        __syncthreads();
    }
    int excl = a[t] - v;
    if (t < P) { poff[t] = excl; pfill[t] = excl; }
    if (t == 0) { poff[P] = E; rowp[N] = E; }
}

// block-synchronous multi-split: scatter (src,dst) into partition buckets
__global__ __launch_bounds__(256) void k_pscatter(const int* __restrict__ esrc,
                                                  const int* __restrict__ edst,
                                                  int* __restrict__ pfill,
                                                  u64* __restrict__ pbuf, int E) {
    __shared__ int hist[128], sc[128], lofs[128], gbase[128];
    __shared__ u32 ss[CHUNK], sd[CHUNK];
    int t = threadIdx.x;
    int c0 = blockIdx.x * CHUNK;
    int cnt = E - c0; if (cnt > CHUNK) cnt = CHUNK;

    if (t < 128) hist[t] = 0;
    __syncthreads();

    u32 s[8], d[8];
    int p[8], r[8];
    #pragma unroll
    for (int j = 0; j < 8; ++j) {
        int i = j * 256 + t;
        if (i < cnt) {
            s[j] = (u32)esrc[c0 + i];
            d[j] = (u32)edst[c0 + i];
            p[j] = (int)(d[j] >> PSHIFT);
            r[j] = atomicAdd(&hist[p[j]], 1);
        }
    }
    __syncthreads();

    if (t < 128) sc[t] = hist[t];
    __syncthreads();
    #pragma unroll
    for (int off = 1; off < 128; off <<= 1) {
        int y = 0;
        if (t < 128 && t >= off) y = sc[t - off];
        __syncthreads();
        if (t < 128) sc[t] += y;
        __syncthreads();
    }
    if (t < 128) {
        lofs[t] = sc[t] - hist[t];
        if (hist[t] > 0) gbase[t] = atomicAdd(&pfill[t], hist[t]);
    }
    __syncthreads();

    #pragma unroll
    for (int j = 0; j < 8; ++j) {
        int i = j * 256 + t;
        if (i < cnt) {
            int idx = lofs[p[j]] + r[j];
            ss[idx] = s[j];
            sd[idx] = d[j];
        }
    }
    __syncthreads();

    for (int i = t; i < cnt; i += 256) {
        u32 dd = sd[i];
        int pp = (int)(dd >> PSHIFT);
        int gpos = gbase[pp] + (i - lofs[pp]);
        pbuf[gpos] = (u64)ss[i] | ((u64)dd << 32);
    }
}

// per-partition: local degree histogram -> rowp/dinv segment -> srcs fill
__global__ __launch_bounds__(256) void k_pfill(const u64* __restrict__ pbuf,
                                               const int* __restrict__ poff,
                                               int* __restrict__ rowp,
                                               int* __restrict__ srcs,
                                               float* __restrict__ dinv, int N) {
    __shared__ int cnt[PSZ];
    __shared__ int wsum[4];
    int p = blockIdx.x, t = threadIdx.x;
    int lane = t & 63, wid = t >> 6;
    int nb0 = p << PSHIFT;
    int ncnt = N - nb0; if (ncnt > PSZ) ncnt = PSZ;
    int b0 = poff[p], b1 = poff[p + 1];
    int bc = b1 - b0;

    for (int i = t; i < PSZ; i += 256) cnt[i] = 0;
    __syncthreads();
    for (int i = t; i < bc; i += 256) {
        u32 d = (u32)(pbuf[b0 + i] >> 32);
        atomicAdd(&cnt[d - nb0], 1);
    }
    __syncthreads();

    int base = t * 4;
    int c[4];
    int ssum = 0;
    #pragma unroll
    for (int j = 0; j < 4; ++j) { c[j] = cnt[base + j]; ssum += c[j]; }
    int incl = ssum;
    #pragma unroll
    for (int off = 1; off < 64; off <<= 1) {
        int y = __shfl_up(incl, off, 64);
        if (lane >= off) incl += y;
    }
    if (lane == 63) wsum[wid] = incl;
    __syncthreads();
    int add = 0;
    for (int w = 0; w < wid; ++w) add += wsum[w];
    int rr = b0 + add + (incl - ssum);
    #pragma unroll
    for (int j = 0; j < 4; ++j) {
        int i = base + j;
        if (i < ncnt) {
            rowp[nb0 + i] = rr;
            dinv[nb0 + i] = rsqrtf((float)(c[j] + 1));   // +1 self loop
        }
        cnt[i] = rr;     // becomes fill cursor
        rr += c[j];
    }
    __syncthreads();

    for (int i = t; i < bc; i += 256) {
        u64 v = pbuf[b0 + i];
        u32 sv = (u32)v;
        u32 d = (u32)(v >> 32);
        int pos = atomicAdd(&cnt[d - nb0], 1);
        srcs[pos] = (int)sv;
    }
}

// ---------------- dtype prep ----------------

__global__ __launch_bounds__(256) void k_prepw(const float* __restrict__ W,
                                               const float* __restrict__ Wih,
                                               const float* __restrict__ Whh,
                                               u16* __restrict__ Wt,
                                               u16* __restrict__ Wihb,
                                               u16* __restrict__ Whhb) {
    int i = blockIdx.x * 256 + threadIdx.x;
    if (i < 128 * 128) {
        int k = i >> 7, c = i & 127;
        Wt[c * 128 + k] = f2bf(W[i]);
    }
    if (i < 3 * 128 * 128) {
        Wihb[i] = f2bf(Wih[i]);
        Whhb[i] = f2bf(Whh[i]);
    }
}

__global__ __launch_bounds__(256) void k_cast1(const float4* __restrict__ a,
                                               u32* __restrict__ ab, int n4) {
    int stride = gridDim.x * 256;
    for (int i = blockIdx.x * 256 + threadIdx.x; i < n4; i += stride) {
        float4 v = a[i];
        ab[i * 2 + 0] = (u32)f2bf(v.x) | ((u32)f2bf(v.y) << 16);
        ab[i * 2 + 1] = (u32)f2bf(v.z) | ((u32)f2bf(v.w) << 16);
    }
}

// ---------------- GEMM1: XW_bf = bf16(X) @ Wt_bf (MFMA, W in LDS) ------

__global__ __launch_bounds__(256) void k_gemm1(const float* __restrict__ X,
                                               const u16* __restrict__ Wt,
                                               u16* __restrict__ XWb, int n) {
    __shared__ u16 Wlds[128 * 128];   // 32 KB, XOR-swizzled rows
    int t = threadIdx.x, w = t >> 6, l = t & 63;
    int lr = l & 15, q = l >> 4;

    for (int cidx = t; cidx < 2048; cidx += 256) {
        int r = cidx >> 4, kc = cidx & 15;
        int dst = r * 128 + ((kc * 8) ^ ((r & 7) << 3));
        *(bf16x8*)(Wlds + dst) = *(const bf16x8*)(Wt + r * 128 + kc * 8);
    }
    __syncthreads();

    int r0 = blockIdx.x * 128;
    int wrow0 = r0 + w * 32;
    int sw = (lr & 7) << 3;
    int ar0 = wrow0 + lr;      if (ar0 > n - 1) ar0 = n - 1;
    int ar1 = wrow0 + 16 + lr; if (ar1 > n - 1) ar1 = n - 1;
    const float* x0 = X + (size_t)ar0 * DIM;
    const float* x1 = X + (size_t)ar1 * DIM;

    f32x4 acc[2][8];
    #pragma unroll
    for (int s = 0; s < 2; ++s)
        #pragma unroll
        for (int c = 0; c < 8; ++c) acc[s][c] = (f32x4){0.f, 0.f, 0.f, 0.f};

    #pragma unroll
    for (int kb = 0; kb < 4; ++kb) {
        int ko = kb * 32 + q * 8;
        float4 f00 = *(const float4*)(x0 + ko), f01 = *(const float4*)(x0 + ko + 4);
        float4 f10 = *(const float4*)(x1 + ko), f11 = *(const float4*)(x1 + ko + 4);
        bf16x8 a0, a1;
        a0[0] = (short)f2bf(f00.x); a0[1] = (short)f2bf(f00.y);
        a0[2] = (short)f2bf(f00.z); a0[3] = (short)f2bf(f00.w);
        a0[4] = (short)f2bf(f01.x); a0[5] = (short)f2bf(f01.y);
        a0[6] = (short)f2bf(f01.z); a0[7] = (short)f2bf(f01.w);
        a1[0] = (short)f2bf(f10.x); a1[1] = (short)f2bf(f10.y);
        a1[2] = (short)f2bf(f10.z); a1[3] = (short)f2bf(f10.w);
        a1[4] = (short)f2bf(f11.x); a1[5] = (short)f2bf(f11.y);
        a1[6] = (short)f2bf(f11.z); a1[7] = (short)f2bf(f11.w);
        int kw = ko ^ sw;
        #pragma unroll
        for (int ct = 0; ct < 8; ++ct) {
            bf16x8 b = *(const bf16x8*)(Wlds + (ct * 16 + lr) * 128 + kw);
            acc[0][ct] = __builtin_amdgcn_mfma_f32_16x16x32_bf16(a0, b, acc[0][ct], 0, 0, 0);
            acc[1][ct] = __builtin_amdgcn_mfma_f32_16x16x32_bf16(a1, b, acc[1][ct], 0, 0, 0);
        }
    }

    #pragma unroll
    for (int s = 0; s < 2; ++s)
        #pragma unroll
        for (int ct = 0; ct < 8; ++ct)
            #pragma unroll
            for (int i = 0; i < 4; ++i) {
                int row = wrow0 + s * 16 + q * 4 + i;
                if (row < n)
                    XWb[(size_t)row * DIM + ct * 16 + lr] = f2bf(acc[s][ct][i]);
            }
}

// ---------------- gather (bf16 in/out) ----------------

__global__ __launch_bounds__(256) void k_gather(const u16* __restrict__ XWb,
                                                const float* __restrict__ dinv,
                                                const int* __restrict__ row_ptr,
                                                const int* __restrict__ srcs,
                                                const float* __restrict__ bias,
                                                u16* __restrict__ Hcb, int n) {
    int node = blockIdx.x * 4 + (threadIdx.x >> 6);
    if (node >= n) return;
    int lane = threadIdx.x & 63;
    int c = lane * 2;

    float di = dinv[node];
    u32 sv = *(const u32*)(XWb + (size_t)node * DIM + c);
    float accx = bias[c]     + bf2f((u16)(sv & 0xffff)) * di * di;
    float accy = bias[c + 1] + bf2f((u16)(sv >> 16))    * di * di;

    int e = row_ptr[node], end = row_ptr[node + 1];
    for (; e + 3 < end; e += 4) {
        int s0 = srcs[e], s1 = srcs[e + 1], s2 = srcs[e + 2], s3 = srcs[e + 3];
        float n0 = dinv[s0] * di, n1 = dinv[s1] * di, n2 = dinv[s2] * di, n3 = dinv[s3] * di;
        u32 v0 = *(const u32*)(XWb + (size_t)s0 * DIM + c);
        u32 v1 = *(const u32*)(XWb + (size_t)s1 * DIM + c);
        u32 v2 = *(const u32*)(XWb + (size_t)s2 * DIM + c);
        u32 v3 = *(const u32*)(XWb + (size_t)s3 * DIM + c);
        accx += bf2f((u16)(v0 & 0xffff)) * n0 + bf2f((u16)(v1 & 0xffff)) * n1
              + bf2f((u16)(v2 & 0xffff)) * n2 + bf2f((u16)(v3 & 0xffff)) * n3;
        accy += bf2f((u16)(v0 >> 16)) * n0 + bf2f((u16)(v1 >> 16)) * n1
              + bf2f((u16)(v2 >> 16)) * n2 + bf2f((u16)(v3 >> 16)) * n3;
    }
    for (; e < end; ++e) {
        int s = srcs[e];
        float nrm = dinv[s] * di;
        u32 v = *(const u32*)(XWb + (size_t)s * DIM + c);
        accx += bf2f((u16)(v & 0xffff)) * nrm;
        accy += bf2f((u16)(v >> 16)) * nrm;
    }
    *(u32*)(Hcb + (size_t)node * DIM + c) = (u32)f2bf(accx) | ((u32)f2bf(accy) << 16);
}

// ---------------- fused GRU (MFMA, weights in LDS) ----------------

__global__ __launch_bounds__(256) void k_gru(const u16* __restrict__ Hcb,
                                             const u16* __restrict__ Xpb,
                                             const u16* __restrict__ Wihb,
                                             const u16* __restrict__ Whhb,
                                             const float* __restrict__ bih,
                                             const float* __restrict__ bhh,
                                             float* __restrict__ Out, int n) {
    __shared__ u16 Wlds[192 * 128];   // 48 KB
    int t = threadIdx.x, w = t >> 6, l = t & 63;
    int lr = l & 15, q = l >> 4;
    int cs = blockIdx.x & 3;
    int rb = blockIdx.x >> 2;
    int c0 = cs * 32;
    int r0 = rb * 128;

    for (int cidx = t; cidx < 3072; cidx += 256) {
        int r = cidx >> 4, kc = cidx & 15;
        int m = (r >= 96);
        int rr = m ? r - 96 : r;
        int g = rr >> 5, cc = rr & 31;
        const u16* src = (m ? Whhb : Wihb) + (size_t)((g << 7) + c0 + cc) * DIM + kc * 8;
        int dst = r * 128 + ((kc * 8) ^ ((r & 7) << 3));
        *(bf16x8*)(Wlds + dst) = *(const bf16x8*)src;
    }
    __syncthreads();

    int wrow0 = r0 + w * 32;
    int sw = (lr & 7) << 3;
    int ar0 = wrow0 + lr;      if (ar0 > n - 1) ar0 = n - 1;
    int ar1 = wrow0 + 16 + lr; if (ar1 > n - 1) ar1 = n - 1;
    const u16* hb0 = Hcb + (size_t)ar0 * DIM;
    const u16* hb1 = Hcb + (size_t)ar1 * DIM;
    const u16* xb0 = Xpb + (size_t)ar0 * DIM;
    const u16* xb1 = Xpb + (size_t)ar1 * DIM;

    f32x4 aI[3][2][2], aH[3][2][2];
    #pragma unroll
    for (int g = 0; g < 3; ++g)
        #pragma unroll
        for (int s = 0; s < 2; ++s)
            #pragma unroll
            for (int c = 0; c < 2; ++c) {
                aI[g][s][c] = (f32x4){0.f, 0.f, 0.f, 0.f};
                aH[g][s][c] = (f32x4){0.f, 0.f, 0.f, 0.f};
            }

    #pragma unroll
    for (int kb = 0; kb < 4; ++kb) {
        int ko = kb * 32 + q * 8;
        bf16x8 hA0 = *(const bf16x8*)(hb0 + ko);
        bf16x8 hA1 = *(const bf16x8*)(hb1 + ko);
        bf16x8 xA0 = *(const bf16x8*)(xb0 + ko);
        bf16x8 xA1 = *(const bf16x8*)(xb1 + ko);
        int kw = ko ^ sw;
        #pragma unroll
        for (int g = 0; g < 3; ++g)
            #pragma unroll
            for (int ct = 0; ct < 2; ++ct) {
                int ridx = (g * 32 + ct * 16 + lr) * 128 + kw;
                bf16x8 bI = *(const bf16x8*)(Wlds + ridx);
                bf16x8 bH = *(const bf16x8*)(Wlds + ridx + 96 * 128);
                aI[g][0][ct] = __builtin_amdgcn_mfma_f32_16x16x32_bf16(hA0, bI, aI[g][0][ct], 0, 0, 0);
                aI[g][1][ct] = __builtin_amdgcn_mfma_f32_16x16x32_bf16(hA1, bI, aI[g][1][ct], 0, 0, 0);
                aH[g][0][ct] = __builtin_amdgcn_mfma_f32_16x16x32_bf16(xA0, bH, aH[g][0][ct], 0, 0, 0);
                aH[g][1][ct] = __builtin_amdgcn_mfma_f32_16x16x32_bf16(xA1, bH, aH[g][1][ct], 0, 0, 0);
            }
    }

    #pragma unroll
    for (int ct = 0; ct < 2; ++ct) {
        int j = c0 + ct * 16 + lr;
        float br = bih[j],       bz = bih[128 + j], bn = bih[256 + j];
        float cr = bhh[j],       cz = bhh[128 + j], cn = bhh[256 + j];
        #pragma unroll
        for (int s = 0; s < 2; ++s)
            #pragma unroll
            for (int i = 0; i < 4; ++i) {
                int row = wrow0 + s * 16 + q * 4 + i;
                if (row >= n) continue;
                float ir = aI[0][s][ct][i] + br;
                float iz = aI[1][s][ct][i] + bz;
                float in_ = aI[2][s][ct][i] + bn;
                float hr = aH[0][s][ct][i] + cr;
                float hz = aH[1][s][ct][i] + cz;
                float hn = aH[2][s][ct][i] + cn;
                float rr = 1.f / (1.f + __expf(-(ir + hr)));
                float zz = 1.f / (1.f + __expf(-(iz + hz)));
                float nn = tanhf(in_ + rr * hn);
                float hp = bf2f((u16)Xpb[(size_t)row * DIM + j]);
                Out[(size_t)row * DIM + j] = (1.f - zz) * nn + zz * hp;
            }
    }
}

// ---------------- host launch ----------------

extern "C" void kernel_launch(void* const* d_in, const int* in_sizes, int n_in,
                              void* d_out, int out_size, void* d_ws, size_t ws_size,
                              hipStream_t stream) {
    const float* x     = (const float*)d_in[0];
    const int*   ei    = (const int*)d_in[1];
    const float* xprev = (const float*)d_in[2];
    const float* W     = (const float*)d_in[3];
    const float* b     = (const float*)d_in[4];
    const float* Wih   = (const float*)d_in[5];
    const float* Whh   = (const float*)d_in[6];
    const float* bih   = (const float*)d_in[7];
    const float* bhh   = (const float*)d_in[8];

    int N = in_sizes[0] / DIM;
    int E = in_sizes[1] / 2;
    int P = (N + PSZ - 1) >> PSHIFT;
    const int* esrc = ei;
    const int* edst = ei + E;

    char* p = (char*)d_ws;
    auto alloc = [&](size_t bytes) {
        char* q = p;
        p += (bytes + 255) & ~(size_t)255;
        return q;
    };
    float* dinv = (float*)alloc((size_t)N * 4);
    int*   rowp = (int*)  alloc((size_t)(N + 1) * 4);
    int*   srcs = (int*)  alloc((size_t)E * 4);
    u16*   Hcb  = (u16*)  alloc((size_t)N * DIM * 2);
    u16*   Xpb  = (u16*)  alloc((size_t)N * DIM * 2);
    u16*   XWb  = (u16*)  alloc((size_t)N * DIM * 2);
    u16*   Wt   = (u16*)  alloc(128 * 128 * 2);
    u16*   Wihb = (u16*)  alloc(3 * 128 * 128 * 2);
    u16*   Whhb = (u16*)  alloc(3 * 128 * 128 * 2);
    int*   pcnt = (int*)  alloc(128 * 4);
    int*   poff = (int*)  alloc(129 * 4);
    int*   pfil = (int*)  alloc(128 * 4);
    u64*   pbuf = (u64*)XWb;   // alias: pbuf dead before k_gemm1 writes XWb
    float* out  = (float*)d_out;

    k_zero    <<<1, 256, 0, stream>>>(pcnt, 128);
    k_pcount  <<<1024, 256, 0, stream>>>(edst, pcnt, E);
    k_pscan   <<<1, 256, 0, stream>>>(pcnt, poff, pfil, rowp, P, N, E);
    int nch = (E + CHUNK - 1) / CHUNK;
    k_pscatter<<<nch, 256, 0, stream>>>(esrc, edst, pfil, pbuf, E);
    k_pfill   <<<P, 256, 0, stream>>>(pbuf, poff, rowp, srcs, dinv, N);
    k_prepw   <<<192, 256, 0, stream>>>(W, Wih, Whh, Wt, Wihb, Whhb);
    int n4 = N * DIM / 4;
    k_cast1   <<<2048, 256, 0, stream>>>((const float4*)xprev, (u32*)Xpb, n4);
    int nrb = (N + 127) / 128;
    k_gemm1   <<<nrb, 256, 0, stream>>>(x, Wt, XWb, N);
    k_gather  <<<(N + 3) / 4, 256, 0, stream>>>(XWb, dinv, rowp, srcs, b, Hcb, N);
    k_gru     <<<nrb * 4, 256, 0, stream>>>(Hcb, Xpb, Wihb, Whhb, bih, bhh, out, N);
}

// Round 6
// 287.346 us; speedup vs baseline: 8.6636x; 1.0814x over previous
//
#include <hip/hip_runtime.h>
#include <hip/hip_bf16.h>
#include <math.h>

#define DIM 128
#define PSHIFT 10          // 1024 nodes per partition
#define PSZ 1024
#define CHUNK 2048

typedef __attribute__((ext_vector_type(8))) short bf16x8;
typedef __attribute__((ext_vector_type(4))) float f32x4;
typedef unsigned short u16;
typedef unsigned int u32;
typedef unsigned long long u64;

__device__ __forceinline__ u16 f2bf(float x) {
    u32 u = __builtin_bit_cast(u32, x);
    u += 0x7fff + ((u >> 16) & 1);          // RNE
    return (u16)(u >> 16);
}
__device__ __forceinline__ float bf2f(u16 h) {
    return __builtin_bit_cast(float, (u32)h << 16);
}

// ---------------- partitioned CSR build ----------------

__global__ __launch_bounds__(256) void k_zero(int* __restrict__ p, int n) {
    int i = blockIdx.x * 256 + threadIdx.x;
    if (i < n) p[i] = 0;
}

__global__ __launch_bounds__(256) void k_pcount(const int* __restrict__ edst,
                                                int* __restrict__ pcnt, int E) {
    __shared__ int h[128];
    int t = threadIdx.x;
    if (t < 128) h[t] = 0;
    __syncthreads();
    int stride = gridDim.x * 256;
    for (int e = blockIdx.x * 256 + t; e < E; e += stride)
        atomicAdd(&h[edst[e] >> PSHIFT], 1);
    __syncthreads();
    if (t < 128 && h[t]) atomicAdd(&pcnt[t], h[t]);
}

__global__ __launch_bounds__(256) void k_pscan(const int* __restrict__ pcnt,
                                               int* __restrict__ poff,
                                               int* __restrict__ pfill,
                                               int* __restrict__ rowp,
                                               int P, int N, int E) {
    __shared__ int a[256];
    int t = threadIdx.x;
    int v = (t < P) ? pcnt[t] : 0;
    a[t] = v;
    __syncthreads();
    #pragma unroll
    for (int off = 1; off < 256; off <<= 1) {
        int y = (t >= off) ? a[t - off] : 0;
        __syncthreads();
        a[t] += y;
        __syncthreads();
    }
    int excl = a[t] - v;
    if (t < P) { poff[t] = excl; pfill[t] = excl; }
    if (t == 0) { poff[P] = E; rowp[N] = E; }
}

__global__ __launch_bounds__(256) void k_pscatter(const int* __restrict__ esrc,
                                                  const int* __restrict__ edst,
                                                  int* __restrict__ pfill,
                                                  u64* __restrict__ pbuf, int E) {
    __shared__ int hist[128], sc[128], lofs[128], gbase[128];
    __shared__ u32 ss[CHUNK], sd[CHUNK];
    int t = threadIdx.x;
    int c0 = blockIdx.x * CHUNK;
    int cnt = E - c0; if (cnt > CHUNK) cnt = CHUNK;

    if (t < 128) hist[t] = 0;
    __syncthreads();

    u32 s[8], d[8];
    int p[8], r[8];
    #pragma unroll
    for (int j = 0; j < 8; ++j) {
        int i = j * 256 + t;
        if (i < cnt) {
            s[j] = (u32)esrc[c0 + i];
            d[j] = (u32)edst[c0 + i];
            p[j] = (int)(d[j] >> PSHIFT);
            r[j] = atomicAdd(&hist[p[j]], 1);
        }
    }
    __syncthreads();

    if (t < 128) sc[t] = hist[t];
    __syncthreads();
    #pragma unroll
    for (int off = 1; off < 128; off <<= 1) {
        int y = 0;
        if (t < 128 && t >= off) y = sc[t - off];
        __syncthreads();
        if (t < 128) sc[t] += y;
        __syncthreads();
    }
    if (t < 128) {
        lofs[t] = sc[t] - hist[t];
        if (hist[t] > 0) gbase[t] = atomicAdd(&pfill[t], hist[t]);
    }
    __syncthreads();

    #pragma unroll
    for (int j = 0; j < 8; ++j) {
        int i = j * 256 + t;
        if (i < cnt) {
            int idx = lofs[p[j]] + r[j];
            ss[idx] = s[j];
            sd[idx] = d[j];
        }
    }
    __syncthreads();

    for (int i = t; i < cnt; i += 256) {
        u32 dd = sd[i];
        int pp = (int)(dd >> PSHIFT);
        int gpos = gbase[pp] + (i - lofs[pp]);
        pbuf[gpos] = (u64)ss[i] | ((u64)dd << 32);
    }
}

__global__ __launch_bounds__(256) void k_pfill(const u64* __restrict__ pbuf,
                                               const int* __restrict__ poff,
                                               int* __restrict__ rowp,
                                               int* __restrict__ srcs,
                                               float* __restrict__ dinv, int N) {
    __shared__ int cnt[PSZ];
    __shared__ int wsum[4];
    int p = blockIdx.x, t = threadIdx.x;
    int lane = t & 63, wid = t >> 6;
    int nb0 = p << PSHIFT;
    int ncnt = N - nb0; if (ncnt > PSZ) ncnt = PSZ;
    int b0 = poff[p], b1 = poff[p + 1];
    int bc = b1 - b0;

    for (int i = t; i < PSZ; i += 256) cnt[i] = 0;
    __syncthreads();
    for (int i = t; i < bc; i += 256) {
        u32 d = (u32)(pbuf[b0 + i] >> 32);
        atomicAdd(&cnt[d - nb0], 1);
    }
    __syncthreads();

    int base = t * 4;
    int c[4];
    int ssum = 0;
    #pragma unroll
    for (int j = 0; j < 4; ++j) { c[j] = cnt[base + j]; ssum += c[j]; }
    int incl = ssum;
    #pragma unroll
    for (int off = 1; off < 64; off <<= 1) {
        int y = __shfl_up(incl, off, 64);
        if (lane >= off) incl += y;
    }
    if (lane == 63) wsum[wid] = incl;
    __syncthreads();
    int add = 0;
    for (int w = 0; w < wid; ++w) add += wsum[w];
    int rr = b0 + add + (incl - ssum);
    #pragma unroll
    for (int j = 0; j < 4; ++j) {
        int i = base + j;
        if (i < ncnt) {
            rowp[nb0 + i] = rr;
            dinv[nb0 + i] = rsqrtf((float)(c[j] + 1));   // +1 self loop
        }
        cnt[i] = rr;     // becomes fill cursor
        rr += c[j];
    }
    __syncthreads();

    for (int i = t; i < bc; i += 256) {
        u64 v = pbuf[b0 + i];
        u32 sv = (u32)v;
        u32 d = (u32)(v >> 32);
        int pos = atomicAdd(&cnt[d - nb0], 1);
        srcs[pos] = (int)sv;
    }
}

// ---------------- dtype prep ----------------

__global__ __launch_bounds__(256) void k_prepw(const float* __restrict__ W,
                                               const float* __restrict__ Wih,
                                               const float* __restrict__ Whh,
                                               u16* __restrict__ Wt,
                                               u16* __restrict__ Wihb,
                                               u16* __restrict__ Whhb) {
    int i = blockIdx.x * 256 + threadIdx.x;
    if (i < 128 * 128) {
        int k = i >> 7, c = i & 127;
        Wt[c * 128 + k] = f2bf(W[i]);
    }
    if (i < 3 * 128 * 128) {
        Wihb[i] = f2bf(Wih[i]);
        Whhb[i] = f2bf(Whh[i]);
    }
}

__global__ __launch_bounds__(256) void k_cast1(const float4* __restrict__ a,
                                               u32* __restrict__ ab, int n4) {
    int stride = gridDim.x * 256;
    for (int i = blockIdx.x * 256 + threadIdx.x; i < n4; i += stride) {
        float4 v = a[i];
        ab[i * 2 + 0] = (u32)f2bf(v.x) | ((u32)f2bf(v.y) << 16);
        ab[i * 2 + 1] = (u32)f2bf(v.z) | ((u32)f2bf(v.w) << 16);
    }
}

// ---------------- GEMM1: XW_bf = bf16(X) @ Wt_bf (MFMA, W in LDS) ------

__global__ __launch_bounds__(256) void k_gemm1(const float* __restrict__ X,
                                               const u16* __restrict__ Wt,
                                               u16* __restrict__ XWb, int n) {
    __shared__ u16 Wlds[128 * 128];   // 32 KB, XOR-swizzled rows
    int t = threadIdx.x, w = t >> 6, l = t & 63;
    int lr = l & 15, q = l >> 4;

    for (int cidx = t; cidx < 2048; cidx += 256) {
        int r = cidx >> 4, kc = cidx & 15;
        int dst = r * 128 + ((kc * 8) ^ ((r & 7) << 3));
        *(bf16x8*)(Wlds + dst) = *(const bf16x8*)(Wt + r * 128 + kc * 8);
    }
    __syncthreads();

    int r0 = blockIdx.x * 128;
    int wrow0 = r0 + w * 32;
    int sw = (lr & 7) << 3;
    int ar0 = wrow0 + lr;      if (ar0 > n - 1) ar0 = n - 1;
    int ar1 = wrow0 + 16 + lr; if (ar1 > n - 1) ar1 = n - 1;
    const float* x0 = X + (size_t)ar0 * DIM;
    const float* x1 = X + (size_t)ar1 * DIM;

    f32x4 acc[2][8];
    #pragma unroll
    for (int s = 0; s < 2; ++s)
        #pragma unroll
        for (int c = 0; c < 8; ++c) acc[s][c] = (f32x4){0.f, 0.f, 0.f, 0.f};

    #pragma unroll
    for (int kb = 0; kb < 4; ++kb) {
        int ko = kb * 32 + q * 8;
        float4 f00 = *(const float4*)(x0 + ko), f01 = *(const float4*)(x0 + ko + 4);
        float4 f10 = *(const float4*)(x1 + ko), f11 = *(const float4*)(x1 + ko + 4);
        bf16x8 a0, a1;
        a0[0] = (short)f2bf(f00.x); a0[1] = (short)f2bf(f00.y);
        a0[2] = (short)f2bf(f00.z); a0[3] = (short)f2bf(f00.w);
        a0[4] = (short)f2bf(f01.x); a0[5] = (short)f2bf(f01.y);
        a0[6] = (short)f2bf(f01.z); a0[7] = (short)f2bf(f01.w);
        a1[0] = (short)f2bf(f10.x); a1[1] = (short)f2bf(f10.y);
        a1[2] = (short)f2bf(f10.z); a1[3] = (short)f2bf(f10.w);
        a1[4] = (short)f2bf(f11.x); a1[5] = (short)f2bf(f11.y);
        a1[6] = (short)f2bf(f11.z); a1[7] = (short)f2bf(f11.w);
        int kw = ko ^ sw;
        #pragma unroll
        for (int ct = 0; ct < 8; ++ct) {
            bf16x8 b = *(const bf16x8*)(Wlds + (ct * 16 + lr) * 128 + kw);
            acc[0][ct] = __builtin_amdgcn_mfma_f32_16x16x32_bf16(a0, b, acc[0][ct], 0, 0, 0);
            acc[1][ct] = __builtin_amdgcn_mfma_f32_16x16x32_bf16(a1, b, acc[1][ct], 0, 0, 0);
        }
    }

    #pragma unroll
    for (int s = 0; s < 2; ++s)
        #pragma unroll
        for (int ct = 0; ct < 8; ++ct)
            #pragma unroll
            for (int i = 0; i < 4; ++i) {
                int row = wrow0 + s * 16 + q * 4 + i;
                if (row < n)
                    XWb[(size_t)row * DIM + ct * 16 + lr] = f2bf(acc[s][ct][i]);
            }
}

// ---------------- gather (bf16 in/out) ----------------

__global__ __launch_bounds__(256) void k_gather(const u16* __restrict__ XWb,
                                                const float* __restrict__ dinv,
                                                const int* __restrict__ row_ptr,
                                                const int* __restrict__ srcs,
                                                const float* __restrict__ bias,
                                                u16* __restrict__ Hcb, int n) {
    int node = blockIdx.x * 4 + (threadIdx.x >> 6);
    if (node >= n) return;
    int lane = threadIdx.x & 63;
    int c = lane * 2;

    float di = dinv[node];
    u32 sv = *(const u32*)(XWb + (size_t)node * DIM + c);
    float accx = bias[c]     + bf2f((u16)(sv & 0xffff)) * di * di;
    float accy = bias[c + 1] + bf2f((u16)(sv >> 16))    * di * di;

    int e = row_ptr[node], end = row_ptr[node + 1];
    for (; e + 3 < end; e += 4) {
        int s0 = srcs[e], s1 = srcs[e + 1], s2 = srcs[e + 2], s3 = srcs[e + 3];
        float n0 = dinv[s0] * di, n1 = dinv[s1] * di, n2 = dinv[s2] * di, n3 = dinv[s3] * di;
        u32 v0 = *(const u32*)(XWb + (size_t)s0 * DIM + c);
        u32 v1 = *(const u32*)(XWb + (size_t)s1 * DIM + c);
        u32 v2 = *(const u32*)(XWb + (size_t)s2 * DIM + c);
        u32 v3 = *(const u32*)(XWb + (size_t)s3 * DIM + c);
        accx += bf2f((u16)(v0 & 0xffff)) * n0 + bf2f((u16)(v1 & 0xffff)) * n1
              + bf2f((u16)(v2 & 0xffff)) * n2 + bf2f((u16)(v3 & 0xffff)) * n3;
        accy += bf2f((u16)(v0 >> 16)) * n0 + bf2f((u16)(v1 >> 16)) * n1
              + bf2f((u16)(v2 >> 16)) * n2 + bf2f((u16)(v3 >> 16)) * n3;
    }
    for (; e < end; ++e) {
        int s = srcs[e];
        float nrm = dinv[s] * di;
        u32 v = *(const u32*)(XWb + (size_t)s * DIM + c);
        accx += bf2f((u16)(v & 0xffff)) * nrm;
        accy += bf2f((u16)(v >> 16)) * nrm;
    }
    *(u32*)(Hcb + (size_t)node * DIM + c) = (u32)f2bf(accx) | ((u32)f2bf(accy) << 16);
}

// ---------------- fused GRU (MFMA, 16 cols/wave, XCD-chunked) ----------
// logical block = rb*8 + cs; cs = 16-col slice; 4 waves x 32 rows = 128 rows.
// LDS: 96 rows (2 x 3 gates x 16 cols) x 128 k, swizzled = 24 KB.

__global__ __launch_bounds__(256) void k_gru(const u16* __restrict__ Hcb,
                                             const u16* __restrict__ Xpb,
                                             const u16* __restrict__ Wihb,
                                             const u16* __restrict__ Whhb,
                                             const float* __restrict__ bih,
                                             const float* __restrict__ bhh,
                                             float* __restrict__ Out, int n) {
    __shared__ u16 Wlds[96 * 128];   // 24 KB
    int t = threadIdx.x, w = t >> 6, l = t & 63;
    int lr = l & 15, q = l >> 4;

    // bijective XCD-chunk transform (m204): contiguous logical blocks per XCD
    int nwg = gridDim.x;
    int qq = nwg >> 3, rr8 = nwg & 7;
    int xcd = blockIdx.x & 7, idx = blockIdx.x >> 3;
    int logical = (xcd < rr8 ? xcd * (qq + 1) : rr8 * (qq + 1) + (xcd - rr8) * qq) + idx;
    int cs = logical & 7;
    int rb = logical >> 3;
    int c0 = cs * 16;
    int r0 = rb * 128;

    // stage 96 weight rows: r = m*48 + g*16 + cc  (m: 0=ih, 1=hh)
    for (int cidx = t; cidx < 1536; cidx += 256) {
        int r = cidx >> 4, kc = cidx & 15;
        int m = (r >= 48);
        int rr = m ? r - 48 : r;
        int g = rr >> 4, cc = rr & 15;
        const u16* src = (m ? Whhb : Wihb) + (size_t)((g << 7) + c0 + cc) * DIM + kc * 8;
        int dst = r * 128 + ((kc * 8) ^ ((r & 7) << 3));
        *(bf16x8*)(Wlds + dst) = *(const bf16x8*)src;
    }
    __syncthreads();

    int wrow0 = r0 + w * 32;
    int sw = (lr & 7) << 3;
    int ar0 = wrow0 + lr;      if (ar0 > n - 1) ar0 = n - 1;
    int ar1 = wrow0 + 16 + lr; if (ar1 > n - 1) ar1 = n - 1;
    const u16* hb0 = Hcb + (size_t)ar0 * DIM;
    const u16* hb1 = Hcb + (size_t)ar1 * DIM;
    const u16* xb0 = Xpb + (size_t)ar0 * DIM;
    const u16* xb1 = Xpb + (size_t)ar1 * DIM;

    f32x4 aI[3][2], aH[3][2];   // [gate][stripe]
    #pragma unroll
    for (int g = 0; g < 3; ++g)
        #pragma unroll
        for (int s = 0; s < 2; ++s) {
            aI[g][s] = (f32x4){0.f, 0.f, 0.f, 0.f};
            aH[g][s] = (f32x4){0.f, 0.f, 0.f, 0.f};
        }

    #pragma unroll
    for (int kb = 0; kb < 4; ++kb) {
        int ko = kb * 32 + q * 8;
        bf16x8 hA0 = *(const bf16x8*)(hb0 + ko);
        bf16x8 hA1 = *(const bf16x8*)(hb1 + ko);
        bf16x8 xA0 = *(const bf16x8*)(xb0 + ko);
        bf16x8 xA1 = *(const bf16x8*)(xb1 + ko);
        int kw = ko ^ sw;
        #pragma unroll
        for (int g = 0; g < 3; ++g) {
            int ridx = (g * 16 + lr) * 128 + kw;
            bf16x8 bI = *(const bf16x8*)(Wlds + ridx);
            bf16x8 bH = *(const bf16x8*)(Wlds + ridx + 48 * 128);
            aI[g][0] = __builtin_amdgcn_mfma_f32_16x16x32_bf16(hA0, bI, aI[g][0], 0, 0, 0);
            aI[g][1] = __builtin_amdgcn_mfma_f32_16x16x32_bf16(hA1, bI, aI[g][1], 0, 0, 0);
            aH[g][0] = __builtin_amdgcn_mfma_f32_16x16x32_bf16(xA0, bH, aH[g][0], 0, 0, 0);
            aH[g][1] = __builtin_amdgcn_mfma_f32_16x16x32_bf16(xA1, bH, aH[g][1], 0, 0, 0);
        }
    }

    int j = c0 + lr;
    float br = bih[j],       bz = bih[128 + j], bn = bih[256 + j];
    float cr = bhh[j],       cz = bhh[128 + j], cn = bhh[256 + j];
    #pragma unroll
    for (int s = 0; s < 2; ++s)
        #pragma unroll
        for (int i = 0; i < 4; ++i) {
            int row = wrow0 + s * 16 + q * 4 + i;
            if (row >= n) continue;
            float ir = aI[0][s][i] + br;
            float iz = aI[1][s][i] + bz;
            float in_ = aI[2][s][i] + bn;
            float hr = aH[0][s][i] + cr;
            float hz = aH[1][s][i] + cz;
            float hn = aH[2][s][i] + cn;
            float rg = 1.f / (1.f + __expf(-(ir + hr)));
            float zg = 1.f / (1.f + __expf(-(iz + hz)));
            float ng = tanhf(in_ + rg * hn);
            float hp = bf2f((u16)Xpb[(size_t)row * DIM + j]);
            Out[(size_t)row * DIM + j] = (1.f - zg) * ng + zg * hp;
        }
}

// ---------------- host launch ----------------

extern "C" void kernel_launch(void* const* d_in, const int* in_sizes, int n_in,
                              void* d_out, int out_size, void* d_ws, size_t ws_size,
                              hipStream_t stream) {
    const float* x     = (const float*)d_in[0];
    const int*   ei    = (const int*)d_in[1];
    const float* xprev = (const float*)d_in[2];
    const float* W     = (const float*)d_in[3];
    const float* b     = (const float*)d_in[4];
    const float* Wih   = (const float*)d_in[5];
    const float* Whh   = (const float*)d_in[6];
    const float* bih   = (const float*)d_in[7];
    const float* bhh   = (const float*)d_in[8];

    int N = in_sizes[0] / DIM;
    int E = in_sizes[1] / 2;
    int P = (N + PSZ - 1) >> PSHIFT;
    const int* esrc = ei;
    const int* edst = ei + E;

    char* p = (char*)d_ws;
    auto alloc = [&](size_t bytes) {
        char* q = p;
        p += (bytes + 255) & ~(size_t)255;
        return q;
    };
    float* dinv = (float*)alloc((size_t)N * 4);
    int*   rowp = (int*)  alloc((size_t)(N + 1) * 4);
    int*   srcs = (int*)  alloc((size_t)E * 4);
    u16*   Hcb  = (u16*)  alloc((size_t)N * DIM * 2);
    u16*   Xpb  = (u16*)  alloc((size_t)N * DIM * 2);
    u16*   XWb  = (u16*)  alloc((size_t)N * DIM * 2);
    u16*   Wt   = (u16*)  alloc(128 * 128 * 2);
    u16*   Wihb = (u16*)  alloc(3 * 128 * 128 * 2);
    u16*   Whhb = (u16*)  alloc(3 * 128 * 128 * 2);
    int*   pcnt = (int*)  alloc(128 * 4);
    int*   poff = (int*)  alloc(129 * 4);
    int*   pfil = (int*)  alloc(128 * 4);
    u64*   pbuf = (u64*)XWb;   // alias: pbuf dead before k_gemm1 writes XWb
    float* out  = (float*)d_out;

    k_zero    <<<1, 256, 0, stream>>>(pcnt, 128);
    k_pcount  <<<1024, 256, 0, stream>>>(edst, pcnt, E);
    k_pscan   <<<1, 256, 0, stream>>>(pcnt, poff, pfil, rowp, P, N, E);
    int nch = (E + CHUNK - 1) / CHUNK;
    k_pscatter<<<nch, 256, 0, stream>>>(esrc, edst, pfil, pbuf, E);
    k_pfill   <<<P, 256, 0, stream>>>(pbuf, poff, rowp, srcs, dinv, N);
    k_prepw   <<<192, 256, 0, stream>>>(W, Wih, Whh, Wt, Wihb, Whhb);
    int n4 = N * DIM / 4;
    k_cast1   <<<2048, 256, 0, stream>>>((const float4*)xprev, (u32*)Xpb, n4);
    int nrb = (N + 127) / 128;
    k_gemm1   <<<nrb, 256, 0, stream>>>(x, Wt, XWb, N);
    k_gather  <<<(N + 3) / 4, 256, 0, stream>>>(XWb, dinv, rowp, srcs, b, Hcb, N);
    k_gru     <<<nrb * 8, 256, 0, stream>>>(Hcb, Xpb, Wihb, Whhb, bih, bhh, out, N);
}

// Round 7
// 279.860 us; speedup vs baseline: 8.8954x; 1.0267x over previous
//
#include <hip/hip_runtime.h>
#include <hip/hip_bf16.h>
#include <math.h>

#define DIM 128
#define PSHIFT 10          // 1024 nodes per partition
#define PSZ 1024
#define CHUNK 2048

typedef __attribute__((ext_vector_type(8))) short bf16x8;
typedef __attribute__((ext_vector_type(4))) float f32x4;
typedef unsigned short u16;
typedef unsigned int u32;
typedef unsigned long long u64;

__device__ __forceinline__ u16 f2bf(float x) {
    u32 u = __builtin_bit_cast(u32, x);
    u += 0x7fff + ((u >> 16) & 1);          // RNE
    return (u16)(u >> 16);
}
__device__ __forceinline__ float bf2f(u16 h) {
    return __builtin_bit_cast(float, (u32)h << 16);
}
__device__ __forceinline__ float fsig(float x) {      // fast sigmoid
    return __builtin_amdgcn_rcpf(1.f + __expf(-x));
}
__device__ __forceinline__ float ftanh(float x) {     // fast tanh
    return 1.f - 2.f * __builtin_amdgcn_rcpf(__expf(2.f * x) + 1.f);
}

// ---------------- partitioned CSR build ----------------

__global__ __launch_bounds__(256) void k_zero(int* __restrict__ p, int n) {
    int i = blockIdx.x * 256 + threadIdx.x;
    if (i < n) p[i] = 0;
}

__global__ __launch_bounds__(256) void k_pcount(const int* __restrict__ edst,
                                                int* __restrict__ pcnt, int E) {
    __shared__ int h[128];
    int t = threadIdx.x;
    if (t < 128) h[t] = 0;
    __syncthreads();
    int stride = gridDim.x * 256;
    for (int e = blockIdx.x * 256 + t; e < E; e += stride)
        atomicAdd(&h[edst[e] >> PSHIFT], 1);
    __syncthreads();
    if (t < 128 && h[t]) atomicAdd(&pcnt[t], h[t]);
}

__global__ __launch_bounds__(256) void k_pscan(const int* __restrict__ pcnt,
                                               int* __restrict__ poff,
                                               int* __restrict__ pfill,
                                               int* __restrict__ rowp,
                                               int P, int N, int E) {
    __shared__ int a[256];
    int t = threadIdx.x;
    int v = (t < P) ? pcnt[t] : 0;
    a[t] = v;
    __syncthreads();
    #pragma unroll
    for (int off = 1; off < 256; off <<= 1) {
        int y = (t >= off) ? a[t - off] : 0;
        __syncthreads();
        a[t] += y;
        __syncthreads();
    }
    int excl = a[t] - v;
    if (t < P) { poff[t] = excl; pfill[t] = excl; }
    if (t == 0) { poff[P] = E; rowp[N] = E; }
}

__global__ __launch_bounds__(256) void k_pscatter(const int* __restrict__ esrc,
                                                  const int* __restrict__ edst,
                                                  int* __restrict__ pfill,
                                                  u64* __restrict__ pbuf, int E) {
    __shared__ int hist[128], sc[128], lofs[128], gbase[128];
    __shared__ u32 ss[CHUNK], sd[CHUNK];
    int t = threadIdx.x;
    int c0 = blockIdx.x * CHUNK;
    int cnt = E - c0; if (cnt > CHUNK) cnt = CHUNK;

    if (t < 128) hist[t] = 0;
    __syncthreads();

    u32 s[8], d[8];
    int p[8], r[8];
    #pragma unroll
    for (int j = 0; j < 8; ++j) {
        int i = j * 256 + t;
        if (i < cnt) {
            s[j] = (u32)esrc[c0 + i];
            d[j] = (u32)edst[c0 + i];
            p[j] = (int)(d[j] >> PSHIFT);
            r[j] = atomicAdd(&hist[p[j]], 1);
        }
    }
    __syncthreads();

    if (t < 128) sc[t] = hist[t];
    __syncthreads();
    #pragma unroll
    for (int off = 1; off < 128; off <<= 1) {
        int y = 0;
        if (t < 128 && t >= off) y = sc[t - off];
        __syncthreads();
        if (t < 128) sc[t] += y;
        __syncthreads();
    }
    if (t < 128) {
        lofs[t] = sc[t] - hist[t];
        if (hist[t] > 0) gbase[t] = atomicAdd(&pfill[t], hist[t]);
    }
    __syncthreads();

    #pragma unroll
    for (int j = 0; j < 8; ++j) {
        int i = j * 256 + t;
        if (i < cnt) {
            int idx = lofs[p[j]] + r[j];
            ss[idx] = s[j];
            sd[idx] = d[j];
        }
    }
    __syncthreads();

    for (int i = t; i < cnt; i += 256) {
        u32 dd = sd[i];
        int pp = (int)(dd >> PSHIFT);
        int gpos = gbase[pp] + (i - lofs[pp]);
        pbuf[gpos] = (u64)ss[i] | ((u64)dd << 32);
    }
}

__global__ __launch_bounds__(256) void k_pfill(const u64* __restrict__ pbuf,
                                               const int* __restrict__ poff,
                                               int* __restrict__ rowp,
                                               int* __restrict__ srcs,
                                               float* __restrict__ dinv, int N) {
    __shared__ int cnt[PSZ];
    __shared__ int wsum[4];
    int p = blockIdx.x, t = threadIdx.x;
    int lane = t & 63, wid = t >> 6;
    int nb0 = p << PSHIFT;
    int ncnt = N - nb0; if (ncnt > PSZ) ncnt = PSZ;
    int b0 = poff[p], b1 = poff[p + 1];
    int bc = b1 - b0;

    for (int i = t; i < PSZ; i += 256) cnt[i] = 0;
    __syncthreads();
    for (int i = t; i < bc; i += 256) {
        u32 d = (u32)(pbuf[b0 + i] >> 32);
        atomicAdd(&cnt[d - nb0], 1);
    }
    __syncthreads();

    int base = t * 4;
    int c[4];
    int ssum = 0;
    #pragma unroll
    for (int j = 0; j < 4; ++j) { c[j] = cnt[base + j]; ssum += c[j]; }
    int incl = ssum;
    #pragma unroll
    for (int off = 1; off < 64; off <<= 1) {
        int y = __shfl_up(incl, off, 64);
        if (lane >= off) incl += y;
    }
    if (lane == 63) wsum[wid] = incl;
    __syncthreads();
    int add = 0;
    for (int w = 0; w < wid; ++w) add += wsum[w];
    int rr = b0 + add + (incl - ssum);
    #pragma unroll
    for (int j = 0; j < 4; ++j) {
        int i = base + j;
        if (i < ncnt) {
            rowp[nb0 + i] = rr;
            dinv[nb0 + i] = rsqrtf((float)(c[j] + 1));   // +1 self loop
        }
        cnt[i] = rr;     // becomes fill cursor
        rr += c[j];
    }
    __syncthreads();

    for (int i = t; i < bc; i += 256) {
        u64 v = pbuf[b0 + i];
        u32 sv = (u32)v;
        u32 d = (u32)(v >> 32);
        int pos = atomicAdd(&cnt[d - nb0], 1);
        srcs[pos] = (int)sv;
    }
}

// ---------------- fused dtype prep (weights + x_prev cast) ----------------

__global__ __launch_bounds__(256) void k_prep(const float* __restrict__ W,
                                              const float* __restrict__ Wih,
                                              const float* __restrict__ Whh,
                                              const float4* __restrict__ xp,
                                              u16* __restrict__ Wt,
                                              u16* __restrict__ Wihb,
                                              u16* __restrict__ Whhb,
                                              u32* __restrict__ Xpb, int n4) {
    int gid = blockIdx.x * 256 + threadIdx.x;
    int stride = gridDim.x * 256;
    for (int i = gid; i < n4; i += stride) {
        float4 v = xp[i];
        Xpb[i * 2 + 0] = (u32)f2bf(v.x) | ((u32)f2bf(v.y) << 16);
        Xpb[i * 2 + 1] = (u32)f2bf(v.z) | ((u32)f2bf(v.w) << 16);
    }
    if (gid < 128 * 128) {
        int k = gid >> 7, c = gid & 127;
        Wt[c * 128 + k] = f2bf(W[gid]);
    }
    if (gid < 3 * 128 * 128) {
        Wihb[gid] = f2bf(Wih[gid]);
        Whhb[gid] = f2bf(Whh[gid]);
    }
}

// ---------------- GEMM1: XW_bf = bf16(X) @ Wt_bf (MFMA, W in LDS) ------

__global__ __launch_bounds__(256) void k_gemm1(const float* __restrict__ X,
                                               const u16* __restrict__ Wt,
                                               u16* __restrict__ XWb, int n) {
    __shared__ u16 Wlds[128 * 128];   // 32 KB, XOR-swizzled rows
    int t = threadIdx.x, w = t >> 6, l = t & 63;
    int lr = l & 15, q = l >> 4;

    for (int cidx = t; cidx < 2048; cidx += 256) {
        int r = cidx >> 4, kc = cidx & 15;
        int dst = r * 128 + ((kc * 8) ^ ((r & 7) << 3));
        *(bf16x8*)(Wlds + dst) = *(const bf16x8*)(Wt + r * 128 + kc * 8);
    }
    __syncthreads();

    int r0 = blockIdx.x * 128;
    int wrow0 = r0 + w * 32;
    int sw = (lr & 7) << 3;
    int ar0 = wrow0 + lr;      if (ar0 > n - 1) ar0 = n - 1;
    int ar1 = wrow0 + 16 + lr; if (ar1 > n - 1) ar1 = n - 1;
    const float* x0 = X + (size_t)ar0 * DIM;
    const float* x1 = X + (size_t)ar1 * DIM;

    f32x4 acc[2][8];
    #pragma unroll
    for (int s = 0; s < 2; ++s)
        #pragma unroll
        for (int c = 0; c < 8; ++c) acc[s][c] = (f32x4){0.f, 0.f, 0.f, 0.f};

    #pragma unroll
    for (int kb = 0; kb < 4; ++kb) {
        int ko = kb * 32 + q * 8;
        float4 f00 = *(const float4*)(x0 + ko), f01 = *(const float4*)(x0 + ko + 4);
        float4 f10 = *(const float4*)(x1 + ko), f11 = *(const float4*)(x1 + ko + 4);
        bf16x8 a0, a1;
        a0[0] = (short)f2bf(f00.x); a0[1] = (short)f2bf(f00.y);
        a0[2] = (short)f2bf(f00.z); a0[3] = (short)f2bf(f00.w);
        a0[4] = (short)f2bf(f01.x); a0[5] = (short)f2bf(f01.y);
        a0[6] = (short)f2bf(f01.z); a0[7] = (short)f2bf(f01.w);
        a1[0] = (short)f2bf(f10.x); a1[1] = (short)f2bf(f10.y);
        a1[2] = (short)f2bf(f10.z); a1[3] = (short)f2bf(f10.w);
        a1[4] = (short)f2bf(f11.x); a1[5] = (short)f2bf(f11.y);
        a1[6] = (short)f2bf(f11.z); a1[7] = (short)f2bf(f11.w);
        int kw = ko ^ sw;
        #pragma unroll
        for (int ct = 0; ct < 8; ++ct) {
            bf16x8 b = *(const bf16x8*)(Wlds + (ct * 16 + lr) * 128 + kw);
            acc[0][ct] = __builtin_amdgcn_mfma_f32_16x16x32_bf16(a0, b, acc[0][ct], 0, 0, 0);
            acc[1][ct] = __builtin_amdgcn_mfma_f32_16x16x32_bf16(a1, b, acc[1][ct], 0, 0, 0);
        }
    }

    #pragma unroll
    for (int s = 0; s < 2; ++s)
        #pragma unroll
        for (int ct = 0; ct < 8; ++ct)
            #pragma unroll
            for (int i = 0; i < 4; ++i) {
                int row = wrow0 + s * 16 + q * 4 + i;
                if (row < n)
                    XWb[(size_t)row * DIM + ct * 16 + lr] = f2bf(acc[s][ct][i]);
            }
}

// ---------------- gather (bf16 in/out, 8-deep MLP) ----------------

__global__ __launch_bounds__(256) void k_gather(const u16* __restrict__ XWb,
                                                const float* __restrict__ dinv,
                                                const int* __restrict__ row_ptr,
                                                const int* __restrict__ srcs,
                                                const float* __restrict__ bias,
                                                u16* __restrict__ Hcb, int n) {
    int node = blockIdx.x * 4 + (threadIdx.x >> 6);
    if (node >= n) return;
    int lane = threadIdx.x & 63;
    int c = lane * 2;

    float di = dinv[node];
    u32 sv = *(const u32*)(XWb + (size_t)node * DIM + c);
    float accx = bias[c]     + bf2f((u16)(sv & 0xffff)) * di * di;
    float accy = bias[c + 1] + bf2f((u16)(sv >> 16))    * di * di;

    int e = row_ptr[node], end = row_ptr[node + 1];
    for (; e + 7 < end; e += 8) {
        int sdx[8]; float nw[8]; u32 vv[8];
        #pragma unroll
        for (int j = 0; j < 8; ++j) sdx[j] = srcs[e + j];
        #pragma unroll
        for (int j = 0; j < 8; ++j) nw[j] = dinv[sdx[j]] * di;
        #pragma unroll
        for (int j = 0; j < 8; ++j)
            vv[j] = *(const u32*)(XWb + (size_t)sdx[j] * DIM + c);
        #pragma unroll
        for (int j = 0; j < 8; ++j) {
            accx += bf2f((u16)(vv[j] & 0xffff)) * nw[j];
            accy += bf2f((u16)(vv[j] >> 16)) * nw[j];
        }
    }
    for (; e < end; ++e) {
        int s = srcs[e];
        float nrm = dinv[s] * di;
        u32 v = *(const u32*)(XWb + (size_t)s * DIM + c);
        accx += bf2f((u16)(v & 0xffff)) * nrm;
        accy += bf2f((u16)(v >> 16)) * nrm;
    }
    *(u32*)(Hcb + (size_t)node * DIM + c) = (u32)f2bf(accx) | ((u32)f2bf(accy) << 16);
}

// ---------------- fused GRU (MFMA, persistent col-slice blocks) --------
// grid = 1536 (6 blocks/CU). cs = logical&7 fixed per block; weights staged
// ONCE; block loops rb = slot, slot+192, ... over 128-row chunks.

__global__ __launch_bounds__(256) void k_gru(const u16* __restrict__ Hcb,
                                             const u16* __restrict__ Xpb,
                                             const u16* __restrict__ Wihb,
                                             const u16* __restrict__ Whhb,
                                             const float* __restrict__ bih,
                                             const float* __restrict__ bhh,
                                             float* __restrict__ Out, int n) {
    __shared__ u16 Wlds[96 * 128];   // 24 KB
    int t = threadIdx.x, w = t >> 6, l = t & 63;
    int lr = l & 15, q = l >> 4;

    // bijective XCD-chunk transform (m204)
    int nwg = gridDim.x;
    int qq = nwg >> 3, rr8 = nwg & 7;
    int xcd = blockIdx.x & 7, idx = blockIdx.x >> 3;
    int logical = (xcd < rr8 ? xcd * (qq + 1) : rr8 * (qq + 1) + (xcd - rr8) * qq) + idx;
    int cs = logical & 7;
    int slot = logical >> 3;
    int nslot = nwg >> 3;
    int c0 = cs * 16;

    // stage 96 weight rows once: r = m*48 + g*16 + cc  (m: 0=ih, 1=hh)
    for (int cidx = t; cidx < 1536; cidx += 256) {
        int r = cidx >> 4, kc = cidx & 15;
        int m = (r >= 48);
        int rr = m ? r - 48 : r;
        int g = rr >> 4, cc = rr & 15;
        const u16* src = (m ? Whhb : Wihb) + (size_t)((g << 7) + c0 + cc) * DIM + kc * 8;
        int dst = r * 128 + ((kc * 8) ^ ((r & 7) << 3));
        *(bf16x8*)(Wlds + dst) = *(const bf16x8*)src;
    }
    __syncthreads();

    int sw = (lr & 7) << 3;
    int j = c0 + lr;
    float br = bih[j],       bz = bih[128 + j], bn = bih[256 + j];
    float cr = bhh[j],       cz = bhh[128 + j], cn = bhh[256 + j];

    int nrb = (n + 127) >> 7;
    for (int rb = slot; rb < nrb; rb += nslot) {
        int wrow0 = rb * 128 + w * 32;
        int ar0 = wrow0 + lr;      if (ar0 > n - 1) ar0 = n - 1;
        int ar1 = wrow0 + 16 + lr; if (ar1 > n - 1) ar1 = n - 1;
        const u16* hb0 = Hcb + (size_t)ar0 * DIM;
        const u16* hb1 = Hcb + (size_t)ar1 * DIM;
        const u16* xb0 = Xpb + (size_t)ar0 * DIM;
        const u16* xb1 = Xpb + (size_t)ar1 * DIM;

        f32x4 aI[3][2], aH[3][2];   // [gate][stripe]
        #pragma unroll
        for (int g = 0; g < 3; ++g)
            #pragma unroll
            for (int s = 0; s < 2; ++s) {
                aI[g][s] = (f32x4){0.f, 0.f, 0.f, 0.f};
                aH[g][s] = (f32x4){0.f, 0.f, 0.f, 0.f};
            }

        #pragma unroll
        for (int kb = 0; kb < 4; ++kb) {
            int ko = kb * 32 + q * 8;
            bf16x8 hA0 = *(const bf16x8*)(hb0 + ko);
            bf16x8 hA1 = *(const bf16x8*)(hb1 + ko);
            bf16x8 xA0 = *(const bf16x8*)(xb0 + ko);
            bf16x8 xA1 = *(const bf16x8*)(xb1 + ko);
            int kw = ko ^ sw;
            #pragma unroll
            for (int g = 0; g < 3; ++g) {
                int ridx = (g * 16 + lr) * 128 + kw;
                bf16x8 bI = *(const bf16x8*)(Wlds + ridx);
                bf16x8 bH = *(const bf16x8*)(Wlds + ridx + 48 * 128);
                aI[g][0] = __builtin_amdgcn_mfma_f32_16x16x32_bf16(hA0, bI, aI[g][0], 0, 0, 0);
                aI[g][1] = __builtin_amdgcn_mfma_f32_16x16x32_bf16(hA1, bI, aI[g][1], 0, 0, 0);
                aH[g][0] = __builtin_amdgcn_mfma_f32_16x16x32_bf16(xA0, bH, aH[g][0], 0, 0, 0);
                aH[g][1] = __builtin_amdgcn_mfma_f32_16x16x32_bf16(xA1, bH, aH[g][1], 0, 0, 0);
            }
        }

        #pragma unroll
        for (int s = 0; s < 2; ++s)
            #pragma unroll
            for (int i = 0; i < 4; ++i) {
                int row = wrow0 + s * 16 + q * 4 + i;
                if (row >= n) continue;
                float ir = aI[0][s][i] + br;
                float iz = aI[1][s][i] + bz;
                float in_ = aI[2][s][i] + bn;
                float hr = aH[0][s][i] + cr;
                float hz = aH[1][s][i] + cz;
                float hn = aH[2][s][i] + cn;
                float rg = fsig(ir + hr);
                float zg = fsig(iz + hz);
                float ng = ftanh(in_ + rg * hn);
                float hp = bf2f((u16)Xpb[(size_t)row * DIM + j]);
                Out[(size_t)row * DIM + j] = (1.f - zg) * ng + zg * hp;
            }
    }
}

// ---------------- host launch ----------------

extern "C" void kernel_launch(void* const* d_in, const int* in_sizes, int n_in,
                              void* d_out, int out_size, void* d_ws, size_t ws_size,
                              hipStream_t stream) {
    const float* x     = (const float*)d_in[0];
    const int*   ei    = (const int*)d_in[1];
    const float* xprev = (const float*)d_in[2];
    const float* W     = (const float*)d_in[3];
    const float* b     = (const float*)d_in[4];
    const float* Wih   = (const float*)d_in[5];
    const float* Whh   = (const float*)d_in[6];
    const float* bih   = (const float*)d_in[7];
    const float* bhh   = (const float*)d_in[8];

    int N = in_sizes[0] / DIM;
    int E = in_sizes[1] / 2;
    int P = (N + PSZ - 1) >> PSHIFT;
    const int* esrc = ei;
    const int* edst = ei + E;

    char* p = (char*)d_ws;
    auto alloc = [&](size_t bytes) {
        char* q = p;
        p += (bytes + 255) & ~(size_t)255;
        return q;
    };
    float* dinv = (float*)alloc((size_t)N * 4);
    int*   rowp = (int*)  alloc((size_t)(N + 1) * 4);
    int*   srcs = (int*)  alloc((size_t)E * 4);
    u16*   Hcb  = (u16*)  alloc((size_t)N * DIM * 2);
    u16*   Xpb  = (u16*)  alloc((size_t)N * DIM * 2);
    u16*   XWb  = (u16*)  alloc((size_t)N * DIM * 2);
    u16*   Wt   = (u16*)  alloc(128 * 128 * 2);
    u16*   Wihb = (u16*)  alloc(3 * 128 * 128 * 2);
    u16*   Whhb = (u16*)  alloc(3 * 128 * 128 * 2);
    int*   pcnt = (int*)  alloc(128 * 4);
    int*   poff = (int*)  alloc(129 * 4);
    int*   pfil = (int*)  alloc(128 * 4);
    u64*   pbuf = (u64*)XWb;   // alias: pbuf dead before k_gemm1 writes XWb
    float* out  = (float*)d_out;

    k_zero    <<<1, 256, 0, stream>>>(pcnt, 128);
    k_pcount  <<<1024, 256, 0, stream>>>(edst, pcnt, E);
    k_pscan   <<<1, 256, 0, stream>>>(pcnt, poff, pfil, rowp, P, N, E);
    int nch = (E + CHUNK - 1) / CHUNK;
    k_pscatter<<<nch, 256, 0, stream>>>(esrc, edst, pfil, pbuf, E);
    k_pfill   <<<P, 256, 0, stream>>>(pbuf, poff, rowp, srcs, dinv, N);
    int n4 = N * DIM / 4;
    k_prep    <<<2048, 256, 0, stream>>>(W, Wih, Whh, (const float4*)xprev,
                                         Wt, Wihb, Whhb, (u32*)Xpb, n4);
    int nrb = (N + 127) / 128;
    k_gemm1   <<<nrb, 256, 0, stream>>>(x, Wt, XWb, N);
    k_gather  <<<(N + 3) / 4, 256, 0, stream>>>(XWb, dinv, rowp, srcs, b, Hcb, N);
    k_gru     <<<1536, 256, 0, stream>>>(Hcb, Xpb, Wihb, Whhb, bih, bhh, out, N);
}

// Round 8
// 274.459 us; speedup vs baseline: 9.0704x; 1.0197x over previous
//
#include <hip/hip_runtime.h>
#include <hip/hip_bf16.h>
#include <math.h>

#define DIM 128
#define PSHIFT 10          // 1024 nodes per partition
#define PSZ 1024
#define CHUNK 2048

typedef __attribute__((ext_vector_type(8))) short bf16x8;
typedef __attribute__((ext_vector_type(4))) float f32x4;
typedef unsigned short u16;
typedef unsigned int u32;
typedef unsigned long long u64;

__device__ __forceinline__ u16 f2bf(float x) {
    u32 u = __builtin_bit_cast(u32, x);
    u += 0x7fff + ((u >> 16) & 1);          // RNE
    return (u16)(u >> 16);
}
__device__ __forceinline__ float bf2f(u16 h) {
    return __builtin_bit_cast(float, (u32)h << 16);
}
__device__ __forceinline__ float fsig(float x) {      // fast sigmoid
    return __builtin_amdgcn_rcpf(1.f + __expf(-x));
}
__device__ __forceinline__ float ftanh(float x) {     // fast tanh
    return 1.f - 2.f * __builtin_amdgcn_rcpf(__expf(2.f * x) + 1.f);
}

// ---------------- partitioned CSR build ----------------

__global__ __launch_bounds__(256) void k_zero(int* __restrict__ p, int n) {
    int i = blockIdx.x * 256 + threadIdx.x;
    if (i < n) p[i] = 0;
}

__global__ __launch_bounds__(256) void k_pcount(const int* __restrict__ edst,
                                                int* __restrict__ pcnt, int E) {
    __shared__ int h[128];
    int t = threadIdx.x;
    if (t < 128) h[t] = 0;
    __syncthreads();
    int stride = gridDim.x * 256;
    for (int e = blockIdx.x * 256 + t; e < E; e += stride)
        atomicAdd(&h[edst[e] >> PSHIFT], 1);
    __syncthreads();
    if (t < 128 && h[t]) atomicAdd(&pcnt[t], h[t]);
}

__global__ __launch_bounds__(256) void k_pscan(const int* __restrict__ pcnt,
                                               int* __restrict__ poff,
                                               int* __restrict__ pfill,
                                               int* __restrict__ rowp,
                                               int P, int N, int E) {
    __shared__ int a[256];
    int t = threadIdx.x;
    int v = (t < P) ? pcnt[t] : 0;
    a[t] = v;
    __syncthreads();
    #pragma unroll
    for (int off = 1; off < 256; off <<= 1) {
        int y = (t >= off) ? a[t - off] : 0;
        __syncthreads();
        a[t] += y;
        __syncthreads();
    }
    int excl = a[t] - v;
    if (t < P) { poff[t] = excl; pfill[t] = excl; }
    if (t == 0) { poff[P] = E; rowp[N] = E; }
}

__global__ __launch_bounds__(256) void k_pscatter(const int* __restrict__ esrc,
                                                  const int* __restrict__ edst,
                                                  int* __restrict__ pfill,
                                                  u64* __restrict__ pbuf, int E) {
    __shared__ int hist[128], sc[128], lofs[128], gbase[128];
    __shared__ u32 ss[CHUNK], sd[CHUNK];
    int t = threadIdx.x;
    int c0 = blockIdx.x * CHUNK;
    int cnt = E - c0; if (cnt > CHUNK) cnt = CHUNK;

    if (t < 128) hist[t] = 0;
    __syncthreads();

    u32 s[8], d[8];
    int p[8], r[8];
    #pragma unroll
    for (int j = 0; j < 8; ++j) {
        int i = j * 256 + t;
        if (i < cnt) {
            s[j] = (u32)esrc[c0 + i];
            d[j] = (u32)edst[c0 + i];
            p[j] = (int)(d[j] >> PSHIFT);
            r[j] = atomicAdd(&hist[p[j]], 1);
        }
    }
    __syncthreads();

    if (t < 128) sc[t] = hist[t];
    __syncthreads();
    #pragma unroll
    for (int off = 1; off < 128; off <<= 1) {
        int y = 0;
        if (t < 128 && t >= off) y = sc[t - off];
        __syncthreads();
        if (t < 128) sc[t] += y;
        __syncthreads();
    }
    if (t < 128) {
        lofs[t] = sc[t] - hist[t];
        if (hist[t] > 0) gbase[t] = atomicAdd(&pfill[t], hist[t]);
    }
    __syncthreads();

    #pragma unroll
    for (int j = 0; j < 8; ++j) {
        int i = j * 256 + t;
        if (i < cnt) {
            int idx = lofs[p[j]] + r[j];
            ss[idx] = s[j];
            sd[idx] = d[j];
        }
    }
    __syncthreads();

    for (int i = t; i < cnt; i += 256) {
        u32 dd = sd[i];
        int pp = (int)(dd >> PSHIFT);
        int gpos = gbase[pp] + (i - lofs[pp]);
        pbuf[gpos] = (u64)ss[i] | ((u64)dd << 32);
    }
}

__global__ __launch_bounds__(256) void k_pfill(const u64* __restrict__ pbuf,
                                               const int* __restrict__ poff,
                                               int* __restrict__ rowp,
                                               int* __restrict__ srcs,
                                               float* __restrict__ dinv, int N) {
    __shared__ int cnt[PSZ];
    __shared__ int wsum[4];
    int p = blockIdx.x, t = threadIdx.x;
    int lane = t & 63, wid = t >> 6;
    int nb0 = p << PSHIFT;
    int ncnt = N - nb0; if (ncnt > PSZ) ncnt = PSZ;
    int b0 = poff[p], b1 = poff[p + 1];
    int bc = b1 - b0;

    for (int i = t; i < PSZ; i += 256) cnt[i] = 0;
    __syncthreads();
    for (int i = t; i < bc; i += 256) {
        u32 d = (u32)(pbuf[b0 + i] >> 32);
        atomicAdd(&cnt[d - nb0], 1);
    }
    __syncthreads();

    int base = t * 4;
    int c[4];
    int ssum = 0;
    #pragma unroll
    for (int j = 0; j < 4; ++j) { c[j] = cnt[base + j]; ssum += c[j]; }
    int incl = ssum;
    #pragma unroll
    for (int off = 1; off < 64; off <<= 1) {
        int y = __shfl_up(incl, off, 64);
        if (lane >= off) incl += y;
    }
    if (lane == 63) wsum[wid] = incl;
    __syncthreads();
    int add = 0;
    for (int w = 0; w < wid; ++w) add += wsum[w];
    int rr = b0 + add + (incl - ssum);
    #pragma unroll
    for (int j = 0; j < 4; ++j) {
        int i = base + j;
        if (i < ncnt) {
            rowp[nb0 + i] = rr;
            dinv[nb0 + i] = rsqrtf((float)(c[j] + 1));   // +1 self loop
        }
        cnt[i] = rr;     // becomes fill cursor
        rr += c[j];
    }
    __syncthreads();

    for (int i = t; i < bc; i += 256) {
        u64 v = pbuf[b0 + i];
        u32 sv = (u32)v;
        u32 d = (u32)(v >> 32);
        int pos = atomicAdd(&cnt[d - nb0], 1);
        srcs[pos] = (int)sv;
    }
}

// ---------------- fused dtype prep (weights + x_prev cast) ----------------

__global__ __launch_bounds__(256) void k_prep(const float* __restrict__ W,
                                              const float* __restrict__ Wih,
                                              const float* __restrict__ Whh,
                                              const float4* __restrict__ xp,
                                              u16* __restrict__ Wt,
                                              u16* __restrict__ Wihb,
                                              u16* __restrict__ Whhb,
                                              u32* __restrict__ Xpb, int n4) {
    int gid = blockIdx.x * 256 + threadIdx.x;
    int stride = gridDim.x * 256;
    for (int i = gid; i < n4; i += stride) {
        float4 v = xp[i];
        Xpb[i * 2 + 0] = (u32)f2bf(v.x) | ((u32)f2bf(v.y) << 16);
        Xpb[i * 2 + 1] = (u32)f2bf(v.z) | ((u32)f2bf(v.w) << 16);
    }
    if (gid < 128 * 128) {
        int k = gid >> 7, c = gid & 127;
        Wt[c * 128 + k] = f2bf(W[gid]);
    }
    if (gid < 3 * 128 * 128) {
        Wihb[gid] = f2bf(Wih[gid]);
        Whhb[gid] = f2bf(Whh[gid]);
    }
}

// ---------------- GEMM1: XW_bf = bf16(X) @ Wt_bf (MFMA, W in LDS) ------

__global__ __launch_bounds__(256) void k_gemm1(const float* __restrict__ X,
                                               const u16* __restrict__ Wt,
                                               u16* __restrict__ XWb, int n) {
    __shared__ u16 Wlds[128 * 128];   // 32 KB, XOR-swizzled rows
    int t = threadIdx.x, w = t >> 6, l = t & 63;
    int lr = l & 15, q = l >> 4;

    for (int cidx = t; cidx < 2048; cidx += 256) {
        int r = cidx >> 4, kc = cidx & 15;
        int dst = r * 128 + ((kc * 8) ^ ((r & 7) << 3));
        *(bf16x8*)(Wlds + dst) = *(const bf16x8*)(Wt + r * 128 + kc * 8);
    }
    __syncthreads();

    int r0 = blockIdx.x * 128;
    int wrow0 = r0 + w * 32;
    int sw = (lr & 7) << 3;
    int ar0 = wrow0 + lr;      if (ar0 > n - 1) ar0 = n - 1;   // clamp: X sized exactly
    int ar1 = wrow0 + 16 + lr; if (ar1 > n - 1) ar1 = n - 1;
    const float* x0 = X + (size_t)ar0 * DIM;
    const float* x1 = X + (size_t)ar1 * DIM;

    f32x4 acc[2][8];
    #pragma unroll
    for (int s = 0; s < 2; ++s)
        #pragma unroll
        for (int c = 0; c < 8; ++c) acc[s][c] = (f32x4){0.f, 0.f, 0.f, 0.f};

    #pragma unroll
    for (int kb = 0; kb < 4; ++kb) {
        int ko = kb * 32 + q * 8;
        float4 f00 = *(const float4*)(x0 + ko), f01 = *(const float4*)(x0 + ko + 4);
        float4 f10 = *(const float4*)(x1 + ko), f11 = *(const float4*)(x1 + ko + 4);
        bf16x8 a0, a1;
        a0[0] = (short)f2bf(f00.x); a0[1] = (short)f2bf(f00.y);
        a0[2] = (short)f2bf(f00.z); a0[3] = (short)f2bf(f00.w);
        a0[4] = (short)f2bf(f01.x); a0[5] = (short)f2bf(f01.y);
        a0[6] = (short)f2bf(f01.z); a0[7] = (short)f2bf(f01.w);
        a1[0] = (short)f2bf(f10.x); a1[1] = (short)f2bf(f10.y);
        a1[2] = (short)f2bf(f10.z); a1[3] = (short)f2bf(f10.w);
        a1[4] = (short)f2bf(f11.x); a1[5] = (short)f2bf(f11.y);
        a1[6] = (short)f2bf(f11.z); a1[7] = (short)f2bf(f11.w);
        int kw = ko ^ sw;
        #pragma unroll
        for (int ct = 0; ct < 8; ++ct) {
            bf16x8 b = *(const bf16x8*)(Wlds + (ct * 16 + lr) * 128 + kw);
            acc[0][ct] = __builtin_amdgcn_mfma_f32_16x16x32_bf16(a0, b, acc[0][ct], 0, 0, 0);
            acc[1][ct] = __builtin_amdgcn_mfma_f32_16x16x32_bf16(a1, b, acc[1][ct], 0, 0, 0);
        }
    }

    #pragma unroll
    for (int s = 0; s < 2; ++s)
        #pragma unroll
        for (int ct = 0; ct < 8; ++ct)
            #pragma unroll
            for (int i = 0; i < 4; ++i) {
                int row = wrow0 + s * 16 + q * 4 + i;
                if (row < n)
                    XWb[(size_t)row * DIM + ct * 16 + lr] = f2bf(acc[s][ct][i]);
            }
}

// ---------------- gather (bf16 in/out, 8-deep MLP) ----------------

__global__ __launch_bounds__(256) void k_gather(const u16* __restrict__ XWb,
                                                const float* __restrict__ dinv,
                                                const int* __restrict__ row_ptr,
                                                const int* __restrict__ srcs,
                                                const float* __restrict__ bias,
                                                u16* __restrict__ Hcb, int n) {
    int node = blockIdx.x * 4 + (threadIdx.x >> 6);
    if (node >= n) return;
    int lane = threadIdx.x & 63;
    int c = lane * 2;

    float di = dinv[node];
    u32 sv = *(const u32*)(XWb + (size_t)node * DIM + c);
    float accx = bias[c]     + bf2f((u16)(sv & 0xffff)) * di * di;
    float accy = bias[c + 1] + bf2f((u16)(sv >> 16))    * di * di;

    int e = row_ptr[node], end = row_ptr[node + 1];
    for (; e + 7 < end; e += 8) {
        int sdx[8]; float nw[8]; u32 vv[8];
        #pragma unroll
        for (int j = 0; j < 8; ++j) sdx[j] = srcs[e + j];
        #pragma unroll
        for (int j = 0; j < 8; ++j) nw[j] = dinv[sdx[j]] * di;
        #pragma unroll
        for (int j = 0; j < 8; ++j)
            vv[j] = *(const u32*)(XWb + (size_t)sdx[j] * DIM + c);
        #pragma unroll
        for (int j = 0; j < 8; ++j) {
            accx += bf2f((u16)(vv[j] & 0xffff)) * nw[j];
            accy += bf2f((u16)(vv[j] >> 16)) * nw[j];
        }
    }
    for (; e < end; ++e) {
        int s = srcs[e];
        float nrm = dinv[s] * di;
        u32 v = *(const u32*)(XWb + (size_t)s * DIM + c);
        accx += bf2f((u16)(v & 0xffff)) * nrm;
        accy += bf2f((u16)(v >> 16)) * nrm;
    }
    *(u32*)(Hcb + (size_t)node * DIM + c) = (u32)f2bf(accx) | ((u32)f2bf(accy) << 16);
}

// ---------------- fused GRU (MFMA, persistent, 16 rows/wave) -----------
// grid = 1536. cs = logical&7 (16-col slice), weights staged once (24 KB).
// Wave = 16 rows x 16 cols -> acc 6 x f32x4 (low VGPR => high occupancy).
// Block chunk = 64 rows; loops rb = slot, slot+192, ...

__global__ __launch_bounds__(256) void k_gru(const u16* __restrict__ Hcb,
                                             const u16* __restrict__ Xpb,
                                             const u16* __restrict__ Wihb,
                                             const u16* __restrict__ Whhb,
                                             const float* __restrict__ bih,
                                             const float* __restrict__ bhh,
                                             float* __restrict__ Out, int n) {
    __shared__ u16 Wlds[96 * 128];   // 24 KB
    int t = threadIdx.x, w = t >> 6, l = t & 63;
    int lr = l & 15, q = l >> 4;

    // bijective XCD-chunk transform (m204)
    int nwg = gridDim.x;
    int qq = nwg >> 3, rr8 = nwg & 7;
    int xcd = blockIdx.x & 7, idx = blockIdx.x >> 3;
    int logical = (xcd < rr8 ? xcd * (qq + 1) : rr8 * (qq + 1) + (xcd - rr8) * qq) + idx;
    int cs = logical & 7;
    int slot = logical >> 3;
    int nslot = nwg >> 3;
    int c0 = cs * 16;

    // stage 96 weight rows once: r = m*48 + g*16 + cc  (m: 0=ih, 1=hh)
    for (int cidx = t; cidx < 1536; cidx += 256) {
        int r = cidx >> 4, kc = cidx & 15;
        int m = (r >= 48);
        int rr = m ? r - 48 : r;
        int g = rr >> 4, cc = rr & 15;
        const u16* src = (m ? Whhb : Wihb) + (size_t)((g << 7) + c0 + cc) * DIM + kc * 8;
        int dst = r * 128 + ((kc * 8) ^ ((r & 7) << 3));
        *(bf16x8*)(Wlds + dst) = *(const bf16x8*)src;
    }
    __syncthreads();

    int sw = (lr & 7) << 3;
    int j = c0 + lr;
    float br = bih[j],       bz = bih[128 + j], bn = bih[256 + j];
    float cr = bhh[j],       cz = bhh[128 + j], cn = bhh[256 + j];

    int nrb = (n + 63) >> 6;
    for (int rb = slot; rb < nrb; rb += nslot) {
        int wrow0 = rb * 64 + w * 16;
        int ar = wrow0 + lr; if (ar > n - 1) ar = n - 1;   // clamped A-row
        const u16* hb = Hcb + (size_t)ar * DIM;
        const u16* xb = Xpb + (size_t)ar * DIM;

        // issue epilogue hp loads early (overlap with MFMA)
        u16 hp16[4];
        #pragma unroll
        for (int i = 0; i < 4; ++i) {
            int row = wrow0 + q * 4 + i; if (row > n - 1) row = n - 1;
            hp16[i] = Xpb[(size_t)row * DIM + j];
        }

        f32x4 aI[3], aH[3];
        #pragma unroll
        for (int g = 0; g < 3; ++g) {
            aI[g] = (f32x4){0.f, 0.f, 0.f, 0.f};
            aH[g] = (f32x4){0.f, 0.f, 0.f, 0.f};
        }

        #pragma unroll
        for (int kb = 0; kb < 4; ++kb) {
            int ko = kb * 32 + q * 8;
            bf16x8 hA = *(const bf16x8*)(hb + ko);
            bf16x8 xA = *(const bf16x8*)(xb + ko);
            int kw = ko ^ sw;
            #pragma unroll
            for (int g = 0; g < 3; ++g) {
                int ridx = (g * 16 + lr) * 128 + kw;
                bf16x8 bI = *(const bf16x8*)(Wlds + ridx);
                bf16x8 bH = *(const bf16x8*)(Wlds + ridx + 48 * 128);
                aI[g] = __builtin_amdgcn_mfma_f32_16x16x32_bf16(hA, bI, aI[g], 0, 0, 0);
                aH[g] = __builtin_amdgcn_mfma_f32_16x16x32_bf16(xA, bH, aH[g], 0, 0, 0);
            }
        }

        #pragma unroll
        for (int i = 0; i < 4; ++i) {
            int row = wrow0 + q * 4 + i;
            if (row >= n) continue;
            float ir = aI[0][i] + br;
            float iz = aI[1][i] + bz;
            float in_ = aI[2][i] + bn;
            float hr = aH[0][i] + cr;
            float hz = aH[1][i] + cz;
            float hn = aH[2][i] + cn;
            float rg = fsig(ir + hr);
            float zg = fsig(iz + hz);
            float ng = ftanh(in_ + rg * hn);
            float hp = bf2f(hp16[i]);
            Out[(size_t)row * DIM + j] = (1.f - zg) * ng + zg * hp;
        }
    }
}

// ---------------- host launch ----------------

extern "C" void kernel_launch(void* const* d_in, const int* in_sizes, int n_in,
                              void* d_out, int out_size, void* d_ws, size_t ws_size,
                              hipStream_t stream) {
    const float* x     = (const float*)d_in[0];
    const int*   ei    = (const int*)d_in[1];
    const float* xprev = (const float*)d_in[2];
    const float* W     = (const float*)d_in[3];
    const float* b     = (const float*)d_in[4];
    const float* Wih   = (const float*)d_in[5];
    const float* Whh   = (const float*)d_in[6];
    const float* bih   = (const float*)d_in[7];
    const float* bhh   = (const float*)d_in[8];

    int N = in_sizes[0] / DIM;
    int E = in_sizes[1] / 2;
    int P = (N + PSZ - 1) >> PSHIFT;
    const int* esrc = ei;
    const int* edst = ei + E;

    char* p = (char*)d_ws;
    auto alloc = [&](size_t bytes) {
        char* q = p;
        p += (bytes + 255) & ~(size_t)255;
        return q;
    };
    float* dinv = (float*)alloc((size_t)N * 4);
    int*   rowp = (int*)  alloc((size_t)(N + 1) * 4);
    int*   srcs = (int*)  alloc((size_t)E * 4);
    u16*   Hcb  = (u16*)  alloc((size_t)N * DIM * 2);
    u16*   Xpb  = (u16*)  alloc((size_t)N * DIM * 2);
    u16*   XWb  = (u16*)  alloc((size_t)N * DIM * 2);
    u16*   Wt   = (u16*)  alloc(128 * 128 * 2);
    u16*   Wihb = (u16*)  alloc(3 * 128 * 128 * 2);
    u16*   Whhb = (u16*)  alloc(3 * 128 * 128 * 2);
    int*   pcnt = (int*)  alloc(128 * 4);
    int*   poff = (int*)  alloc(129 * 4);
    int*   pfil = (int*)  alloc(128 * 4);
    u64*   pbuf = (u64*)XWb;   // alias: pbuf dead before k_gemm1 writes XWb
    float* out  = (float*)d_out;

    k_zero    <<<1, 256, 0, stream>>>(pcnt, 128);
    k_pcount  <<<1024, 256, 0, stream>>>(edst, pcnt, E);
    k_pscan   <<<1, 256, 0, stream>>>(pcnt, poff, pfil, rowp, P, N, E);
    int nch = (E + CHUNK - 1) / CHUNK;
    k_pscatter<<<nch, 256, 0, stream>>>(esrc, edst, pfil, pbuf, E);
    k_pfill   <<<P, 256, 0, stream>>>(pbuf, poff, rowp, srcs, dinv, N);
    int n4 = N * DIM / 4;
    k_prep    <<<2048, 256, 0, stream>>>(W, Wih, Whh, (const float4*)xprev,
                                         Wt, Wihb, Whhb, (u32*)Xpb, n4);
    int nrb = (N + 127) / 128;
    k_gemm1   <<<nrb, 256, 0, stream>>>(x, Wt, XWb, N);
    k_gather  <<<(N + 3) / 4, 256, 0, stream>>>(XWb, dinv, rowp, srcs, b, Hcb, N);
    k_gru     <<<1536, 256, 0, stream>>>(Hcb, Xpb, Wihb, Whhb, bih, bhh, out, N);
}

// Round 9
// 273.171 us; speedup vs baseline: 9.1132x; 1.0047x over previous
//
#include <hip/hip_runtime.h>
#include <hip/hip_bf16.h>
#include <math.h>

#define DIM 128
#define PSHIFT 10          // 1024 nodes per partition
#define PSZ 1024
#define CHUNK 4096

typedef __attribute__((ext_vector_type(8))) short bf16x8;
typedef __attribute__((ext_vector_type(4))) float f32x4;
typedef __attribute__((ext_vector_type(2))) float f32x2;
typedef unsigned short u16;
typedef unsigned char u8;
typedef unsigned int u32;
typedef unsigned long long u64;

__device__ __forceinline__ u16 f2bf(float x) {
    u32 u = __builtin_bit_cast(u32, x);
    u += 0x7fff + ((u >> 16) & 1);          // RNE
    return (u16)(u >> 16);
}
__device__ __forceinline__ float bf2f(u16 h) {
    return __builtin_bit_cast(float, (u32)h << 16);
}
__device__ __forceinline__ float fsig(float x) {      // fast sigmoid
    return __builtin_amdgcn_rcpf(1.f + __expf(-x));
}
__device__ __forceinline__ float ftanh(float x) {     // fast tanh
    return 1.f - 2.f * __builtin_amdgcn_rcpf(__expf(2.f * x) + 1.f);
}
__device__ __forceinline__ u8 f2fp8(float v) {        // OCP e4m3 via HW cvt
    int pk = __builtin_amdgcn_cvt_pk_fp8_f32(v, v, 0, false);
    return (u8)(pk & 0xff);
}

// ---------------- partitioned CSR build ----------------

__global__ __launch_bounds__(256) void k_zero(int* __restrict__ p, int n) {
    int i = blockIdx.x * 256 + threadIdx.x;
    if (i < n) p[i] = 0;
}

__global__ __launch_bounds__(256) void k_pcount(const int* __restrict__ edst,
                                                int* __restrict__ pcnt, int E) {
    __shared__ int h[128];
    int t = threadIdx.x;
    if (t < 128) h[t] = 0;
    __syncthreads();
    int stride = gridDim.x * 256;
    for (int e = blockIdx.x * 256 + t; e < E; e += stride)
        atomicAdd(&h[edst[e] >> PSHIFT], 1);
    __syncthreads();
    if (t < 128 && h[t]) atomicAdd(&pcnt[t], h[t]);
}

__global__ __launch_bounds__(256) void k_pscan(const int* __restrict__ pcnt,
                                               int* __restrict__ poff,
                                               int* __restrict__ pfill,
                                               int* __restrict__ rowp,
                                               int P, int N, int E) {
    __shared__ int a[256];
    int t = threadIdx.x;
    int v = (t < P) ? pcnt[t] : 0;
    a[t] = v;
    __syncthreads();
    #pragma unroll
    for (int off = 1; off < 256; off <<= 1) {
        int y = (t >= off) ? a[t - off] : 0;
        __syncthreads();
        a[t] += y;
        __syncthreads();
    }
    int excl = a[t] - v;
    if (t < P) { poff[t] = excl; pfill[t] = excl; }
    if (t == 0) { poff[P] = E; rowp[N] = E; }
}

__global__ __launch_bounds__(256) void k_pscatter(const int* __restrict__ esrc,
                                                  const int* __restrict__ edst,
                                                  int* __restrict__ pfill,
                                                  u64* __restrict__ pbuf, int E) {
    __shared__ int hist[128], sc[128], lofs[128], gbase[128];
    __shared__ u32 ss[CHUNK], sd[CHUNK];
    int t = threadIdx.x;
    int c0 = blockIdx.x * CHUNK;
    int cnt = E - c0; if (cnt > CHUNK) cnt = CHUNK;

    if (t < 128) hist[t] = 0;
    __syncthreads();

    u32 s[16], d[16];
    int p[16], r[16];
    #pragma unroll
    for (int j = 0; j < 16; ++j) {
        int i = j * 256 + t;
        if (i < cnt) {
            s[j] = (u32)esrc[c0 + i];
            d[j] = (u32)edst[c0 + i];
            p[j] = (int)(d[j] >> PSHIFT);
            r[j] = atomicAdd(&hist[p[j]], 1);
        }
    }
    __syncthreads();

    if (t < 128) sc[t] = hist[t];
    __syncthreads();
    #pragma unroll
    for (int off = 1; off < 128; off <<= 1) {
        int y = 0;
        if (t < 128 && t >= off) y = sc[t - off];
        __syncthreads();
        if (t < 128) sc[t] += y;
        __syncthreads();
    }
    if (t < 128) {
        lofs[t] = sc[t] - hist[t];
        if (hist[t] > 0) gbase[t] = atomicAdd(&pfill[t], hist[t]);
    }
    __syncthreads();

    #pragma unroll
    for (int j = 0; j < 16; ++j) {
        int i = j * 256 + t;
        if (i < cnt) {
            int idx = lofs[p[j]] + r[j];
            ss[idx] = s[j];
            sd[idx] = d[j];
        }
    }
    __syncthreads();

    for (int i = t; i < cnt; i += 256) {
        u32 dd = sd[i];
        int pp = (int)(dd >> PSHIFT);
        int gpos = gbase[pp] + (i - lofs[pp]);
        pbuf[gpos] = (u64)ss[i] | ((u64)dd << 32);
    }
}

__global__ __launch_bounds__(256) void k_pfill(const u64* __restrict__ pbuf,
                                               const int* __restrict__ poff,
                                               int* __restrict__ rowp,
                                               int* __restrict__ srcs,
                                               float* __restrict__ dinv, int N) {
    __shared__ int cnt[PSZ];
    __shared__ int wsum[4];
    int p = blockIdx.x, t = threadIdx.x;
    int lane = t & 63, wid = t >> 6;
    int nb0 = p << PSHIFT;
    int ncnt = N - nb0; if (ncnt > PSZ) ncnt = PSZ;
    int b0 = poff[p], b1 = poff[p + 1];
    int bc = b1 - b0;

    for (int i = t; i < PSZ; i += 256) cnt[i] = 0;
    __syncthreads();
    for (int i = t; i < bc; i += 256) {
        u32 d = (u32)(pbuf[b0 + i] >> 32);
        atomicAdd(&cnt[d - nb0], 1);
    }
    __syncthreads();

    int base = t * 4;
    int c[4];
    int ssum = 0;
    #pragma unroll
    for (int j = 0; j < 4; ++j) { c[j] = cnt[base + j]; ssum += c[j]; }
    int incl = ssum;
    #pragma unroll
    for (int off = 1; off < 64; off <<= 1) {
        int y = __shfl_up(incl, off, 64);
        if (lane >= off) incl += y;
    }
    if (lane == 63) wsum[wid] = incl;
    __syncthreads();
    int add = 0;
    for (int w = 0; w < wid; ++w) add += wsum[w];
    int rr = b0 + add + (incl - ssum);
    #pragma unroll
    for (int j = 0; j < 4; ++j) {
        int i = base + j;
        if (i < ncnt) {
            rowp[nb0 + i] = rr;
            dinv[nb0 + i] = rsqrtf((float)(c[j] + 1));   // +1 self loop
        }
        cnt[i] = rr;     // becomes fill cursor
        rr += c[j];
    }
    __syncthreads();

    for (int i = t; i < bc; i += 256) {
        u64 v = pbuf[b0 + i];
        u32 sv = (u32)v;
        u32 d = (u32)(v >> 32);
        int pos = atomicAdd(&cnt[d - nb0], 1);
        srcs[pos] = (int)sv;
    }
}

// ---------------- fused dtype prep (weights + x_prev cast) ----------------

__global__ __launch_bounds__(256) void k_prep(const float* __restrict__ W,
                                              const float* __restrict__ Wih,
                                              const float* __restrict__ Whh,
                                              const float4* __restrict__ xp,
                                              u16* __restrict__ Wt,
                                              u16* __restrict__ Wihb,
                                              u16* __restrict__ Whhb,
                                              u32* __restrict__ Xpb, int n4) {
    int gid = blockIdx.x * 256 + threadIdx.x;
    int stride = gridDim.x * 256;
    for (int i = gid; i < n4; i += stride) {
        float4 v = xp[i];
        Xpb[i * 2 + 0] = (u32)f2bf(v.x) | ((u32)f2bf(v.y) << 16);
        Xpb[i * 2 + 1] = (u32)f2bf(v.z) | ((u32)f2bf(v.w) << 16);
    }
    if (gid < 128 * 128) {
        int k = gid >> 7, c = gid & 127;
        Wt[c * 128 + k] = f2bf(W[gid]);
    }
    if (gid < 3 * 128 * 128) {
        Wihb[gid] = f2bf(Wih[gid]);
        Whhb[gid] = f2bf(Whh[gid]);
    }
}

// ---------------- GEMM1: XW8 = fp8( (bf16(X) @ Wt) * dinv[row] ) -------
// W in LDS (swizzled); output prescaled by dinv and quantized to e4m3.

__global__ __launch_bounds__(256) void k_gemm1(const float* __restrict__ X,
                                               const u16* __restrict__ Wt,
                                               const float* __restrict__ dinv,
                                               u8* __restrict__ XW8, int n) {
    __shared__ u16 Wlds[128 * 128];   // 32 KB, XOR-swizzled rows
    int t = threadIdx.x, w = t >> 6, l = t & 63;
    int lr = l & 15, q = l >> 4;

    for (int cidx = t; cidx < 2048; cidx += 256) {
        int r = cidx >> 4, kc = cidx & 15;
        int dst = r * 128 + ((kc * 8) ^ ((r & 7) << 3));
        *(bf16x8*)(Wlds + dst) = *(const bf16x8*)(Wt + r * 128 + kc * 8);
    }
    __syncthreads();

    int r0 = blockIdx.x * 128;
    int wrow0 = r0 + w * 32;
    int sw = (lr & 7) << 3;
    int ar0 = wrow0 + lr;      if (ar0 > n - 1) ar0 = n - 1;   // clamp: X sized exactly
    int ar1 = wrow0 + 16 + lr; if (ar1 > n - 1) ar1 = n - 1;
    const float* x0 = X + (size_t)ar0 * DIM;
    const float* x1 = X + (size_t)ar1 * DIM;

    f32x4 acc[2][8];
    #pragma unroll
    for (int s = 0; s < 2; ++s)
        #pragma unroll
        for (int c = 0; c < 8; ++c) acc[s][c] = (f32x4){0.f, 0.f, 0.f, 0.f};

    #pragma unroll
    for (int kb = 0; kb < 4; ++kb) {
        int ko = kb * 32 + q * 8;
        float4 f00 = *(const float4*)(x0 + ko), f01 = *(const float4*)(x0 + ko + 4);
        float4 f10 = *(const float4*)(x1 + ko), f11 = *(const float4*)(x1 + ko + 4);
        bf16x8 a0, a1;
        a0[0] = (short)f2bf(f00.x); a0[1] = (short)f2bf(f00.y);
        a0[2] = (short)f2bf(f00.z); a0[3] = (short)f2bf(f00.w);
        a0[4] = (short)f2bf(f01.x); a0[5] = (short)f2bf(f01.y);
        a0[6] = (short)f2bf(f01.z); a0[7] = (short)f2bf(f01.w);
        a1[0] = (short)f2bf(f10.x); a1[1] = (short)f2bf(f10.y);
        a1[2] = (short)f2bf(f10.z); a1[3] = (short)f2bf(f10.w);
        a1[4] = (short)f2bf(f11.x); a1[5] = (short)f2bf(f11.y);
        a1[6] = (short)f2bf(f11.z); a1[7] = (short)f2bf(f11.w);
        int kw = ko ^ sw;
        #pragma unroll
        for (int ct = 0; ct < 8; ++ct) {
            bf16x8 b = *(const bf16x8*)(Wlds + (ct * 16 + lr) * 128 + kw);
            acc[0][ct] = __builtin_amdgcn_mfma_f32_16x16x32_bf16(a0, b, acc[0][ct], 0, 0, 0);
            acc[1][ct] = __builtin_amdgcn_mfma_f32_16x16x32_bf16(a1, b, acc[1][ct], 0, 0, 0);
        }
    }

    // prescale by dinv[row], quantize to fp8
    float dv[2][4];
    #pragma unroll
    for (int s = 0; s < 2; ++s)
        #pragma unroll
        for (int i = 0; i < 4; ++i) {
            int row = wrow0 + s * 16 + q * 4 + i; if (row > n - 1) row = n - 1;
            dv[s][i] = dinv[row];
        }
    #pragma unroll
    for (int s = 0; s < 2; ++s)
        #pragma unroll
        for (int ct = 0; ct < 8; ++ct)
            #pragma unroll
            for (int i = 0; i < 4; ++i) {
                int row = wrow0 + s * 16 + q * 4 + i;
                if (row < n)
                    XW8[(size_t)row * DIM + ct * 16 + lr] = f2fp8(acc[s][ct][i] * dv[s][i]);
            }
}

// ---------------- gather (fp8 in, bf16 out) ----------------
// h[d] = dinv[d] * (sum_src XWs[src] + XWs[d]) + bias

__global__ __launch_bounds__(256) void k_gather(const u8* __restrict__ XW8,
                                                const float* __restrict__ dinv,
                                                const int* __restrict__ row_ptr,
                                                const int* __restrict__ srcs,
                                                const float* __restrict__ bias,
                                                u16* __restrict__ Hcb, int n) {
    int node = blockIdx.x * 4 + (threadIdx.x >> 6);
    if (node >= n) return;
    int lane = threadIdx.x & 63;
    int c = lane * 2;

    u16 sv = *(const u16*)(XW8 + (size_t)node * DIM + c);
    f32x2 sf = __builtin_amdgcn_cvt_pk_f32_fp8((int)(u32)sv, false);
    float accx = sf[0], accy = sf[1];   // self term (prescaled)

    int e = row_ptr[node], end = row_ptr[node + 1];
    for (; e + 7 < end; e += 8) {
        int sdx[8]; u16 vv[8];
        #pragma unroll
        for (int j = 0; j < 8; ++j) sdx[j] = srcs[e + j];
        #pragma unroll
        for (int j = 0; j < 8; ++j)
            vv[j] = *(const u16*)(XW8 + (size_t)sdx[j] * DIM + c);
        #pragma unroll
        for (int j = 0; j < 8; ++j) {
            f32x2 f = __builtin_amdgcn_cvt_pk_f32_fp8((int)(u32)vv[j], false);
            accx += f[0];
            accy += f[1];
        }
    }
    for (; e < end; ++e) {
        u16 v = *(const u16*)(XW8 + (size_t)srcs[e] * DIM + c);
        f32x2 f = __builtin_amdgcn_cvt_pk_f32_fp8((int)(u32)v, false);
        accx += f[0];
        accy += f[1];
    }
    float di = dinv[node];
    float ox = accx * di + bias[c];
    float oy = accy * di + bias[c + 1];
    *(u32*)(Hcb + (size_t)node * DIM + c) = (u32)f2bf(ox) | ((u32)f2bf(oy) << 16);
}

// ---------------- fused GRU (MFMA, B-frags in registers, no LDS) -------
// Persistent grid 1536; cs = 16-col slice fixed per block; B (24 bf16x8)
// hoisted to registers before the row loop. Inner loop: 2 global A loads
// per kb + 6 MFMA; no ds_read, no barriers.

__global__ __launch_bounds__(256) void k_gru(const u16* __restrict__ Hcb,
                                             const u16* __restrict__ Xpb,
                                             const u16* __restrict__ Wihb,
                                             const u16* __restrict__ Whhb,
                                             const float* __restrict__ bih,
                                             const float* __restrict__ bhh,
                                             float* __restrict__ Out, int n) {
    int t = threadIdx.x, w = t >> 6, l = t & 63;
    int lr = l & 15, q = l >> 4;

    // bijective XCD-chunk transform (m204)
    int nwg = gridDim.x;
    int qq = nwg >> 3, rr8 = nwg & 7;
    int xcd = blockIdx.x & 7, idx = blockIdx.x >> 3;
    int logical = (xcd < rr8 ? xcd * (qq + 1) : rr8 * (qq + 1) + (xcd - rr8) * qq) + idx;
    int cs = logical & 7;
    int slot = logical >> 3;
    int nslot = nwg >> 3;
    int c0 = cs * 16;

    // hoist all B-fragments into registers (96 VGPR)
    bf16x8 bI[4][3], bH[4][3];
    #pragma unroll
    for (int kb = 0; kb < 4; ++kb)
        #pragma unroll
        for (int g = 0; g < 3; ++g) {
            size_t off = (size_t)(g * 128 + c0 + lr) * DIM + kb * 32 + q * 8;
            bI[kb][g] = *(const bf16x8*)(Wihb + off);
            bH[kb][g] = *(const bf16x8*)(Whhb + off);
        }

    int j = c0 + lr;
    float br = bih[j],       bz = bih[128 + j], bn = bih[256 + j];
    float cr = bhh[j],       cz = bhh[128 + j], cn = bhh[256 + j];

    int nrb = (n + 63) >> 6;
    for (int rb = slot; rb < nrb; rb += nslot) {
        int wrow0 = rb * 64 + w * 16;
        int ar = wrow0 + lr; if (ar > n - 1) ar = n - 1;   // clamped A-row
        const u16* hb = Hcb + (size_t)ar * DIM;
        const u16* xb = Xpb + (size_t)ar * DIM;

        // epilogue hp loads issued early
        u16 hp16[4];
        #pragma unroll
        for (int i = 0; i < 4; ++i) {
            int row = wrow0 + q * 4 + i; if (row > n - 1) row = n - 1;
            hp16[i] = Xpb[(size_t)row * DIM + j];
        }

        f32x4 aI[3], aH[3];
        #pragma unroll
        for (int g = 0; g < 3; ++g) {
            aI[g] = (f32x4){0.f, 0.f, 0.f, 0.f};
            aH[g] = (f32x4){0.f, 0.f, 0.f, 0.f};
        }

        #pragma unroll
        for (int kb = 0; kb < 4; ++kb) {
            int ko = kb * 32 + q * 8;
            bf16x8 hA = *(const bf16x8*)(hb + ko);
            bf16x8 xA = *(const bf16x8*)(xb + ko);
            #pragma unroll
            for (int g = 0; g < 3; ++g) {
                aI[g] = __builtin_amdgcn_mfma_f32_16x16x32_bf16(hA, bI[kb][g], aI[g], 0, 0, 0);
                aH[g] = __builtin_amdgcn_mfma_f32_16x16x32_bf16(xA, bH[kb][g], aH[g], 0, 0, 0);
            }
        }

        #pragma unroll
        for (int i = 0; i < 4; ++i) {
            int row = wrow0 + q * 4 + i;
            if (row >= n) continue;
            float ir = aI[0][i] + br;
            float iz = aI[1][i] + bz;
            float in_ = aI[2][i] + bn;
            float hr = aH[0][i] + cr;
            float hz = aH[1][i] + cz;
            float hn = aH[2][i] + cn;
            float rg = fsig(ir + hr);
            float zg = fsig(iz + hz);
            float ng = ftanh(in_ + rg * hn);
            float hp = bf2f(hp16[i]);
            Out[(size_t)row * DIM + j] = (1.f - zg) * ng + zg * hp;
        }
    }
}

// ---------------- host launch ----------------

extern "C" void kernel_launch(void* const* d_in, const int* in_sizes, int n_in,
                              void* d_out, int out_size, void* d_ws, size_t ws_size,
                              hipStream_t stream) {
    const float* x     = (const float*)d_in[0];
    const int*   ei    = (const int*)d_in[1];
    const float* xprev = (const float*)d_in[2];
    const float* W     = (const float*)d_in[3];
    const float* b     = (const float*)d_in[4];
    const float* Wih   = (const float*)d_in[5];
    const float* Whh   = (const float*)d_in[6];
    const float* bih   = (const float*)d_in[7];
    const float* bhh   = (const float*)d_in[8];

    int N = in_sizes[0] / DIM;
    int E = in_sizes[1] / 2;
    int P = (N + PSZ - 1) >> PSHIFT;
    const int* esrc = ei;
    const int* edst = ei + E;

    char* p = (char*)d_ws;
    auto alloc = [&](size_t bytes) {
        char* q = p;
        p += (bytes + 255) & ~(size_t)255;
        return q;
    };
    float* dinv = (float*)alloc((size_t)N * 4);
    int*   rowp = (int*)  alloc((size_t)(N + 1) * 4);
    int*   srcs = (int*)  alloc((size_t)E * 4);
    u16*   Hcb  = (u16*)  alloc((size_t)N * DIM * 2);
    u16*   Xpb  = (u16*)  alloc((size_t)N * DIM * 2);
    size_t xwsz = (size_t)N * DIM;             // fp8 bytes
    size_t pbsz = (size_t)E * 8;               // pbuf bytes
    u8*    XW8  = (u8*)   alloc(xwsz > pbsz ? xwsz : pbsz);
    u16*   Wt   = (u16*)  alloc(128 * 128 * 2);
    u16*   Wihb = (u16*)  alloc(3 * 128 * 128 * 2);
    u16*   Whhb = (u16*)  alloc(3 * 128 * 128 * 2);
    int*   pcnt = (int*)  alloc(128 * 4);
    int*   poff = (int*)  alloc(129 * 4);
    int*   pfil = (int*)  alloc(128 * 4);
    u64*   pbuf = (u64*)XW8;   // alias: pbuf dead before k_gemm1 writes XW8
    float* out  = (float*)d_out;

    k_zero    <<<1, 256, 0, stream>>>(pcnt, 128);
    k_pcount  <<<1024, 256, 0, stream>>>(edst, pcnt, E);
    k_pscan   <<<1, 256, 0, stream>>>(pcnt, poff, pfil, rowp, P, N, E);
    int nch = (E + CHUNK - 1) / CHUNK;
    k_pscatter<<<nch, 256, 0, stream>>>(esrc, edst, pfil, pbuf, E);
    k_pfill   <<<P, 256, 0, stream>>>(pbuf, poff, rowp, srcs, dinv, N);
    int n4 = N * DIM / 4;
    k_prep    <<<2048, 256, 0, stream>>>(W, Wih, Whh, (const float4*)xprev,
                                         Wt, Wihb, Whhb, (u32*)Xpb, n4);
    int nrb = (N + 127) / 128;
    k_gemm1   <<<nrb, 256, 0, stream>>>(x, Wt, dinv, XW8, N);
    k_gather  <<<(N + 3) / 4, 256, 0, stream>>>(XW8, dinv, rowp, srcs, b, Hcb, N);
    k_gru     <<<1536, 256, 0, stream>>>(Hcb, Xpb, Wihb, Whhb, bih, bhh, out, N);
}